// Round 16
// baseline (407.352 us; speedup 1.0000x reference)
//
#include <hip/hip_runtime.h>
#include <hip/hip_bf16.h>

// Problem geometry (fixed by the reference):
// B=4, C=256, H=W=112, ps=7, N=49, nP=256 windows/batch, NH=8, d=32.
// Inputs fp32. d_out is FP32: [out | shortcut], each (B,C,H,W).

#define PS 7
#define NWIN_N 49
#define CH 256
#define HH 112
#define WW 112
#define BB 4
#define NHEAD 8
#define HD 32

static constexpr size_t ELEMS = (size_t)BB * CH * HH * WW;      // 12,845,056
static constexpr size_t SZ    = ELEMS * 2;                      // 25,690,112 B (one bf16 plane)

typedef __attribute__((ext_vector_type(8))) short short8;
typedef __attribute__((ext_vector_type(4))) float f32x4;

static __device__ __forceinline__ unsigned short bf16_bits(float v) {
    __hip_bfloat16 h = __float2bfloat16(v);
    return *reinterpret_cast<unsigned short*>(&h);
}

// async global->LDS, 16B per lane; lptr wave-uniform, gptr per-lane.
static __device__ __forceinline__ void gload_lds16(const void* g, void* l) {
    __builtin_amdgcn_global_load_lds(
        (const __attribute__((address_space(1))) unsigned int*)g,
        (__attribute__((address_space(3))) unsigned int*)l, 16, 0, 0);
}

// ---------------------------------------------------------------------------
// 1) LayerNorm over C + window partition -> patches[(b*256+p)*49+i][c] (bf16)
// ---------------------------------------------------------------------------
__global__ __launch_bounds__(256) void ln_partition_kernel(
    const float* __restrict__ x, const float* __restrict__ gamma,
    const float* __restrict__ beta, __hip_bfloat16* __restrict__ patches)
{
    int blk = blockIdx.x;
    int seg = blk % 7;
    int bh = blk / 7;
    int h = bh % HH, b = bh / HH;
    int w0 = seg * 16;
    int tid = threadIdx.x;

    __shared__ float X[256][17];
    __shared__ float mus[16], rstds[16];

    #pragma unroll
    for (int l = 0; l < 16; ++l) {
        int idx = l * 256 + tid;
        int c = idx >> 4, wl = idx & 15;
        X[c][wl] = x[((size_t)(b * CH + c) * HH + h) * WW + w0 + wl];
    }
    __syncthreads();

    if (tid < 16) {
        float s = 0.f, ss = 0.f;
        for (int c = 0; c < 256; ++c) { float v = X[c][tid]; s += v; ss += v * v; }
        float mu = s * (1.f / 256.f);
        float var = ss * (1.f / 256.f) - mu * mu;
        mus[tid] = mu;
        rstds[tid] = rsqrtf(var + 1e-5f);
    }
    __syncthreads();

    int c = tid;
    float g = gamma[c], be = beta[c];
    int hp = h / PS, r = h - hp * PS;
    #pragma unroll
    for (int wl = 0; wl < 16; ++wl) {
        int w = w0 + wl;
        int wp = w / PS, cc = w - wp * PS;
        int win = (b * 16 + hp) * 16 + wp;
        int i = r * PS + cc;
        float v = (X[c][wl] - mus[wl]) * rstds[wl] * g + be;
        patches[((size_t)win * NWIN_N + i) * CH + c] = __float2bfloat16(v);
    }
}

// ---------------------------------------------------------------------------
// 2) shortcut: fp32 -> fp32 copy (float4)
// ---------------------------------------------------------------------------
__global__ __launch_bounds__(256) void copy_f32_kernel(
    const float* __restrict__ x, float* __restrict__ out)
{
    size_t i = ((size_t)blockIdx.x * 256 + threadIdx.x) * 4;
    *(float4*)(out + i) = *(const float4*)(x + i);
}

// ---------------------------------------------------------------------------
// prep: W fp32 [Kreal][N] -> Wt bf16 [Npad][Kpad] k-major, zero padded
// ---------------------------------------------------------------------------
__global__ __launch_bounds__(256) void prep_wt_kernel(
    const float* __restrict__ W, unsigned short* __restrict__ Wt,
    int Kreal, int N, int Kpad, int Npad)
{
    int idx = blockIdx.x * 256 + threadIdx.x;
    if (idx >= Npad * Kpad) return;
    int n = idx / Kpad, k = idx - n * Kpad;
    float v = (n < N && k < Kreal) ? W[(size_t)k * N + n] : 0.f;
    Wt[idx] = bf16_bits(v);
}

// ---------------------------------------------------------------------------
// prep for qkv_cross with aligned-segment remap (q@0, k@56, v@112); [256][64].
// ---------------------------------------------------------------------------
__global__ __launch_bounds__(256) void prep_wt_qkvc_kernel(
    const float* __restrict__ W, unsigned short* __restrict__ Wt)
{
    int idx = blockIdx.x * 256 + threadIdx.x;
    if (idx >= 256 * 64) return;
    int n = idx >> 6, k = idx & 63;
    int s = -1;
    if (n < 49) s = n;
    else if (n >= 56 && n < 105) s = n - 7;
    else if (n >= 112 && n < 161) s = n - 14;
    float v = (s >= 0 && k < 49) ? W[(size_t)k * 147 + s] : 0.f;
    Wt[idx] = bf16_bits(v);
}

__global__ __launch_bounds__(192) void prep_bias_c_kernel(
    const float* __restrict__ b, float* __restrict__ bc)
{
    int n = threadIdx.x;   // < 192
    int s = -1;
    if (n < 49) s = n;
    else if (n >= 56 && n < 105) s = n - 7;
    else if (n >= 112 && n < 161) s = n - 14;
    bc[n] = (s >= 0) ? b[s] : 0.f;
}

// ---------------------------------------------------------------------------
// bias prep: rpb [169][8] -> biasb[8][64][64] fp32 padded.
// ---------------------------------------------------------------------------
__global__ __launch_bounds__(256) void bias_prep_kernel(
    const float* __restrict__ rpb, float* __restrict__ biasb)
{
    int idx = blockIdx.x * 256 + threadIdx.x;   // < 32768
    int head = idx >> 12;
    int rem = idx & 4095;
    int i = rem >> 6, j = rem & 63;
    float v;
    if (j >= NWIN_N) v = -1e9f;
    else if (i >= NWIN_N) v = 0.f;
    else {
        int ri = i / 7, ci = i - ri * 7;
        int rj = j / 7, cj = j - rj * 7;
        v = rpb[((ri - rj + 6) * 13 + (ci - cj + 6)) * NHEAD + head];
    }
    biasb[idx] = v;
}

// ---------------------------------------------------------------------------
// Unified MFMA GEMM, BM=128 BN=128 BK=64 (m97 geometry), 256 thr = 4 waves
// (2x2, each wave 64x64 -> 4x4 fragments, 32 MFMA/k-step).
// Staging via global_load_lds(16B): linear LDS dest, pre-swizzled global
// source, same XOR on reads (rule #21). Single 32KB LDS union buffer
// (A rows [128][64] | W rows [128][64]); C-epilogue restages into it as
// [128][128] with a 16-slot XOR swizzle, then coalesced 16B row stores.
// XCD-chunked tile swizzle (all call sites have ntiles % 8 == 0).
// ---------------------------------------------------------------------------
__global__ __launch_bounds__(256) void gemm_mfma_kernel(
    const __hip_bfloat16* __restrict__ A1p, const __hip_bfloat16* __restrict__ A2p,
    int K1, const unsigned short* __restrict__ Wt, const float* __restrict__ bias,
    __hip_bfloat16* __restrict__ Cb, float* __restrict__ Cf,
    int M, int N, int K, int pitchN)
{
    __shared__ __align__(16) unsigned short S[2 * 128 * 64];   // 32 KB
    unsigned short* Wl = S + 128 * 64;
    const unsigned short* A1 = (const unsigned short*)A1p;
    const unsigned short* A2 = (const unsigned short*)A2p;

    const int nb = gridDim.x;
    const int ntiles = nb * gridDim.y;
    const int bid = blockIdx.y * nb + blockIdx.x;
    const int chunk = ntiles >> 3;
    const int tile = (bid & 7) * chunk + (bid >> 3);
    const int m0 = (tile / nb) * 128, n0 = (tile % nb) * 128;

    const int tid = threadIdx.x, lane = tid & 63, wave = tid >> 6;
    const int wm = wave >> 1, wn = wave & 1;
    const int lr = lane & 15, lk = lane >> 4;

    f32x4 acc[4][4];
    #pragma unroll
    for (int i = 0; i < 4; ++i)
        #pragma unroll
        for (int j = 0; j < 4; ++j) acc[i][j] = (f32x4){0.f, 0.f, 0.f, 0.f};

    for (int k0 = 0; k0 < K; k0 += 64) {
        // ---- A: 1024 slots of 16B ----
        #pragma unroll
        for (int i = 0; i < 4; ++i) {
            int s_lin = i * 256 + tid;
            int row = s_lin >> 3, sl = s_lin & 7;
            int c8 = ((sl ^ (row & 7)) << 3);
            int k = k0 + c8;
            const unsigned short* src = (k < K1)
                ? A1 + (size_t)(m0 + row) * K1 + k
                : A2 + (size_t)(m0 + row) * (K - K1) + (k - K1);
            gload_lds16(src, S + (size_t)(i * 256 + wave * 64) * 8);
        }
        // ---- W: 1024 slots (128 rows) ----
        #pragma unroll
        for (int i = 0; i < 4; ++i) {
            int s_lin = i * 256 + tid;
            int row = s_lin >> 3, sl = s_lin & 7;
            int c8 = ((sl ^ (row & 7)) << 3);
            gload_lds16(Wt + (size_t)(n0 + row) * K + k0 + c8,
                        Wl + (size_t)(i * 256 + wave * 64) * 8);
        }
        __syncthreads();
        #pragma unroll
        for (int kk = 0; kk < 64; kk += 32) {
            short8 a[4], w[4];
            #pragma unroll
            for (int mi = 0; mi < 4; ++mi) {
                int r = wm * 64 + mi * 16 + lr;
                int sl = (kk >> 3) + lk;
                a[mi] = *(const short8*)&S[(r << 6) + (((sl) ^ (r & 7)) << 3)];
            }
            #pragma unroll
            for (int nj = 0; nj < 4; ++nj) {
                int r = wn * 64 + nj * 16 + lr;
                int sl = (kk >> 3) + lk;
                w[nj] = *(const short8*)&Wl[(r << 6) + (((sl) ^ (r & 7)) << 3)];
            }
            #pragma unroll
            for (int mi = 0; mi < 4; ++mi)
                #pragma unroll
                for (int nj = 0; nj < 4; ++nj)
                    acc[mi][nj] = __builtin_amdgcn_mfma_f32_16x16x32_bf16(
                        a[mi], w[nj], acc[mi][nj], 0, 0, 0);
        }
        __syncthreads();
    }

    if (Cb) {
        if ((pitchN & 7) == 0) {
            // stage C tile [128][128] into S with 16-slot XOR swizzle
            #pragma unroll
            for (int nj = 0; nj < 4; ++nj) {
                int n = n0 + wn * 64 + nj * 16 + lr;
                float bv = (bias && n < N) ? bias[n] : 0.f;
                int col = wn * 64 + nj * 16 + lr;
                int sl0 = col >> 3, c7 = col & 7;
                #pragma unroll
                for (int mi = 0; mi < 4; ++mi)
                    #pragma unroll
                    for (int r = 0; r < 4; ++r) {
                        int row = wm * 64 + mi * 16 + lk * 4 + r;
                        int slS = (sl0 & 8) | ((sl0 ^ row) & 7);
                        S[(row << 7) + (slS << 3) + c7] = bf16_bits(acc[mi][nj][r] + bv);
                    }
            }
            __syncthreads();
            #pragma unroll
            for (int i = 0; i < 8; ++i) {
                int s = tid + 256 * i;          // 0..2047
                int row = s >> 4, sl = s & 15;
                if (n0 + sl * 8 + 8 <= pitchN) {
                    int slS = (sl & 8) | ((sl ^ row) & 7);
                    *(short8*)((unsigned short*)Cb + (size_t)(m0 + row) * pitchN + n0 + sl * 8) =
                        *(const short8*)&S[(row << 7) + (slS << 3)];
                }
            }
        } else {
            #pragma unroll
            for (int nj = 0; nj < 4; ++nj) {
                int n = n0 + wn * 64 + nj * 16 + lr;
                if (n >= N) continue;
                float bv = bias ? bias[n] : 0.f;
                #pragma unroll
                for (int mi = 0; mi < 4; ++mi) {
                    #pragma unroll
                    for (int r = 0; r < 4; ++r) {
                        int m = m0 + wm * 64 + mi * 16 + lk * 4 + r;
                        ((unsigned short*)Cb)[(size_t)m * pitchN + n] =
                            bf16_bits(acc[mi][nj][r] + bv);
                    }
                }
            }
        }
    } else {
        #pragma unroll
        for (int mi = 0; mi < 4; ++mi) {
            #pragma unroll
            for (int r = 0; r < 4; ++r) {
                int m = m0 + wm * 64 + mi * 16 + lk * 4 + r;
                int b = m / 12544, rem = m - b * 12544;
                int p = rem / 49, t = rem - p * 49;
                int h = (p >> 4) * 7 + t / 7, w = (p & 15) * 7 + (t % 7);
                size_t ob = ((size_t)(b * 256) * HH + h) * WW + w;
                #pragma unroll
                for (int nj = 0; nj < 4; ++nj) {
                    int ch = n0 + wn * 64 + nj * 16 + lr;
                    Cf[ob + (size_t)ch * (HH * WW)] = acc[mi][nj][r];
                }
            }
        }
    }
}

// ---------------------------------------------------------------------------
// 4) local windowed attention, MFMA. One wave per (win, head).
// ---------------------------------------------------------------------------
__global__ __launch_bounds__(64) void local_attn_mfma_kernel(
    const __hip_bfloat16* __restrict__ qkv,   // [50176][768] q|k|v
    const float* __restrict__ biasb,          // [8][64][64] fp32 padded
    __hip_bfloat16* __restrict__ outp)        // [50176][256]
{
    __shared__ __align__(16) unsigned short VT_lds[32][72];
    __shared__ __align__(16) unsigned short P_lds[16][72];

    const int win  = blockIdx.x >> 3;
    const int head = blockIdx.x & 7;
    const int lane = threadIdx.x;
    const int lr = lane & 15, lk = lane >> 4;
    const unsigned short* q16 = (const unsigned short*)qkv;
    const size_t rowbase = (size_t)win * NWIN_N;
    const float scale = 0.17677669529663687f;   // 32^-0.5

    for (int t = 0; t < 32; ++t) {
        int idx = lane + 64 * t;
        int j = idx >> 5, d = idx & 31;
        unsigned short v = 0;
        if (j < NWIN_N) v = q16[(rowbase + j) * 768 + 512 + head * HD + d];
        VT_lds[d][j] = v;
    }

    short8 kf[4], qf[4];
    #pragma unroll
    for (int jt = 0; jt < 4; ++jt) {
        int j = jt * 16 + lr;
        short8 f = *(const short8*)(q16 + (rowbase + j) * 768 + 256 + head * HD + lk * 8);
        if (j >= NWIN_N) {
            #pragma unroll
            for (int e = 0; e < 8; ++e) f[e] = 0;
        }
        kf[jt] = f;
    }
    #pragma unroll
    for (int it = 0; it < 4; ++it) {
        int i = it * 16 + lr;
        qf[it] = *(const short8*)(q16 + (rowbase + i) * 768 + head * HD + lk * 8);
    }
    __syncthreads();

    #pragma unroll
    for (int it = 0; it < 4; ++it) {
        const int i = it * 16 + lr;
        f32x4 sacc[4];
        #pragma unroll
        for (int jt = 0; jt < 4; ++jt) {
            f32x4 z = (f32x4){0.f, 0.f, 0.f, 0.f};
            sacc[jt] = __builtin_amdgcn_mfma_f32_16x16x32_bf16(kf[jt], qf[it], z, 0, 0, 0);
        }
        const float* brow = biasb + head * 4096 + i * 64;
        float sv[4][4];
        float mt = -1e30f;
        #pragma unroll
        for (int jt = 0; jt < 4; ++jt) {
            float4 bv = *(const float4*)&brow[jt * 16 + lk * 4];
            sv[jt][0] = sacc[jt][0] * scale + bv.x;
            sv[jt][1] = sacc[jt][1] * scale + bv.y;
            sv[jt][2] = sacc[jt][2] * scale + bv.z;
            sv[jt][3] = sacc[jt][3] * scale + bv.w;
            #pragma unroll
            for (int r = 0; r < 4; ++r) mt = fmaxf(mt, sv[jt][r]);
        }
        mt = fmaxf(mt, __shfl_xor(mt, 16, 64));
        mt = fmaxf(mt, __shfl_xor(mt, 32, 64));
        float psum = 0.f;
        #pragma unroll
        for (int jt = 0; jt < 4; ++jt) {
            float p0 = __expf(sv[jt][0] - mt);
            float p1 = __expf(sv[jt][1] - mt);
            float p2 = __expf(sv[jt][2] - mt);
            float p3 = __expf(sv[jt][3] - mt);
            psum += (p0 + p1) + (p2 + p3);
            uint2 wv;
            wv.x = (unsigned)bf16_bits(p0) | ((unsigned)bf16_bits(p1) << 16);
            wv.y = (unsigned)bf16_bits(p2) | ((unsigned)bf16_bits(p3) << 16);
            *(uint2*)&P_lds[lr][jt * 16 + lk * 4] = wv;
        }
        psum += __shfl_xor(psum, 16, 64);
        psum += __shfl_xor(psum, 32, 64);
        __syncthreads();

        f32x4 oacc[2];
        oacc[0] = (f32x4){0.f, 0.f, 0.f, 0.f};
        oacc[1] = (f32x4){0.f, 0.f, 0.f, 0.f};
        #pragma unroll
        for (int kst = 0; kst < 2; ++kst) {
            short8 bfv = *(const short8*)&P_lds[lr][kst * 32 + lk * 8];
            #pragma unroll
            for (int dt = 0; dt < 2; ++dt) {
                short8 af = *(const short8*)&VT_lds[dt * 16 + lr][kst * 32 + lk * 8];
                oacc[dt] = __builtin_amdgcn_mfma_f32_16x16x32_bf16(af, bfv, oacc[dt], 0, 0, 0);
            }
        }
        if (i < NWIN_N) {
            float inv = 1.f / psum;
            unsigned short* orow = (unsigned short*)outp + (rowbase + i) * CH + head * HD;
            #pragma unroll
            for (int dt = 0; dt < 2; ++dt) {
                uint2 wv;
                wv.x = (unsigned)bf16_bits(oacc[dt][0] * inv)
                     | ((unsigned)bf16_bits(oacc[dt][1] * inv) << 16);
                wv.y = (unsigned)bf16_bits(oacc[dt][2] * inv)
                     | ((unsigned)bf16_bits(oacc[dt][3] * inv) << 16);
                *(uint2*)&orow[dt * 16 + lk * 4] = wv;
            }
        }
        __syncthreads();
    }
}

// ---------------------------------------------------------------------------
// 5) cross-channel attention, MFMA flash. qkvc pitch 168: q@0, k@56, v@112.
// ---------------------------------------------------------------------------
__global__ __launch_bounds__(256) void cross_attn_mfma_kernel(
    const __hip_bfloat16* __restrict__ qkv,   // [262144][168]
    __hip_bfloat16* __restrict__ outp)        // [262144][64] padded
{
    __shared__ __align__(16) unsigned short K_lds[64][72];
    __shared__ __align__(16) unsigned short VT_lds[64][72];
    __shared__ __align__(16) unsigned short P_lds[2][64][72]; // [0] doubles as V-scratch

    const int bc = blockIdx.x;
    const size_t base = (size_t)bc * 256;
    const int tid  = threadIdx.x;
    const int lane = tid & 63;
    const int wave = tid >> 6;
    const int i0w  = wave * 64;
    const int lr   = lane & 15;
    const int lk   = lane >> 4;
    const int prow = wave * 16 + lr;

    const unsigned short* q16 = (const unsigned short*)qkv;
    const float inv7 = 1.f / 7.f;   // 49^-0.5
    const short8 zf = (short8){0, 0, 0, 0, 0, 0, 0, 0};

    short8 qf[4][2];
    #pragma unroll
    for (int it = 0; it < 4; ++it) {
        const unsigned short* qrow = q16 + (base + i0w + it * 16 + lr) * 168;
        #pragma unroll
        for (int kst = 0; kst < 2; ++kst) {
            int k0 = lk * 8 + kst * 32;
            qf[it][kst] = (k0 <= 48) ? *(const short8*)(qrow + k0) : zf;
        }
    }

    float m_run[4], l_run[4];
    f32x4 acc_o[4][4];   // [dt][it]
    #pragma unroll
    for (int it = 0; it < 4; ++it) { m_run[it] = -1e30f; l_run[it] = 0.f; }
    #pragma unroll
    for (int dt = 0; dt < 4; ++dt)
        #pragma unroll
        for (int it = 0; it < 4; ++it) acc_o[dt][it] = (f32x4){0.f, 0.f, 0.f, 0.f};

    for (int jt4 = 0; jt4 < 4; ++jt4) {
        const int j0 = jt4 * 64;
        {
            const int jr = tid >> 3, c8 = (tid & 7) * 8;
            #pragma unroll
            for (int h = 0; h < 2; ++h) {
                int jj = jr + h * 32;
                const unsigned short* row = q16 + (base + j0 + jj) * 168;
                *(short8*)&K_lds[jj][c8]    = (c8 <= 48) ? *(const short8*)(row + 56 + c8) : zf;
                *(short8*)&P_lds[0][jj][c8] = (c8 <= 48) ? *(const short8*)(row + 112 + c8) : zf;
            }
        }
        __syncthreads();
        {
            const int jj = tid & 63, dg = tid >> 6;
            #pragma unroll
            for (int e = 0; e < 16; ++e) {
                int d = dg * 16 + e;
                VT_lds[d][jj] = P_lds[0][jj][d];
            }
        }
        __syncthreads();

        #pragma unroll
        for (int it = 0; it < 4; ++it) {
            unsigned short* prowp = &P_lds[it & 1][prow][0];
            f32x4 sacc[4];
            #pragma unroll
            for (int jt = 0; jt < 4; ++jt) sacc[jt] = (f32x4){0.f, 0.f, 0.f, 0.f};
            #pragma unroll
            for (int kst = 0; kst < 2; ++kst) {
                #pragma unroll
                for (int jt = 0; jt < 4; ++jt) {
                    short8 af = *(const short8*)&K_lds[jt * 16 + lr][lk * 8 + kst * 32];
                    sacc[jt] = __builtin_amdgcn_mfma_f32_16x16x32_bf16(
                        af, qf[it][kst], sacc[jt], 0, 0, 0);
                }
            }
            float mt = -1e30f;
            #pragma unroll
            for (int jt = 0; jt < 4; ++jt)
                #pragma unroll
                for (int r = 0; r < 4; ++r) mt = fmaxf(mt, sacc[jt][r]);
            mt = fmaxf(mt, __shfl_xor(mt, 16, 64));
            mt = fmaxf(mt, __shfl_xor(mt, 32, 64));
            float mnew = fmaxf(m_run[it], mt * inv7);
            float corr = __expf(m_run[it] - mnew);
            m_run[it] = mnew;
            l_run[it] *= corr;
            #pragma unroll
            for (int dt = 0; dt < 4; ++dt)
                #pragma unroll
                for (int r = 0; r < 4; ++r) acc_o[dt][it][r] *= corr;

            float psum = 0.f;
            #pragma unroll
            for (int jt = 0; jt < 4; ++jt) {
                float p0 = __expf(sacc[jt][0] * inv7 - mnew);
                float p1 = __expf(sacc[jt][1] * inv7 - mnew);
                float p2 = __expf(sacc[jt][2] * inv7 - mnew);
                float p3 = __expf(sacc[jt][3] * inv7 - mnew);
                psum += (p0 + p1) + (p2 + p3);
                uint2 wv;
                wv.x = (unsigned)bf16_bits(p0) | ((unsigned)bf16_bits(p1) << 16);
                wv.y = (unsigned)bf16_bits(p2) | ((unsigned)bf16_bits(p3) << 16);
                *(uint2*)(prowp + jt * 16 + lk * 4) = wv;
            }
            psum += __shfl_xor(psum, 16, 64);
            psum += __shfl_xor(psum, 32, 64);
            l_run[it] += psum;

            #pragma unroll
            for (int kst = 0; kst < 2; ++kst) {
                short8 bfv = *(const short8*)(prowp + kst * 32 + lk * 8);
                #pragma unroll
                for (int dt = 0; dt < 4; ++dt) {
                    short8 af = *(const short8*)&VT_lds[dt * 16 + lr][kst * 32 + lk * 8];
                    acc_o[dt][it] = __builtin_amdgcn_mfma_f32_16x16x32_bf16(
                        af, bfv, acc_o[dt][it], 0, 0, 0);
                }
            }
        }
        __syncthreads();
    }

    #pragma unroll
    for (int it = 0; it < 4; ++it) {
        float inv = 1.f / l_run[it];
        unsigned short* orow = (unsigned short*)outp + (base + i0w + it * 16 + lr) * 64;
        #pragma unroll
        for (int dt = 0; dt < 4; ++dt) {
            uint2 wv;
            wv.x = (unsigned)bf16_bits(acc_o[dt][it][0] * inv)
                 | ((unsigned)bf16_bits(acc_o[dt][it][1] * inv) << 16);
            wv.y = (unsigned)bf16_bits(acc_o[dt][it][2] * inv)
                 | ((unsigned)bf16_bits(acc_o[dt][it][3] * inv) << 16);
            *(uint2*)&orow[dt * 16 + lk * 4] = wv;
        }
    }
}

// ---------------------------------------------------------------------------
// 6a) FUSED transpose + pad: patches -> pc_pad[((b*256+c)*256+p)*64+t]
// ---------------------------------------------------------------------------
__global__ __launch_bounds__(256) void transpose_pad_kernel(
    const __hip_bfloat16* __restrict__ patches, unsigned short* __restrict__ pc_pad)
{
    __shared__ __hip_bfloat16 T[64][66];
    int b = blockIdx.z;
    int r0 = blockIdx.y * 64, c0 = blockIdx.x * 64;
    const __hip_bfloat16* s = patches + (size_t)b * 12544 * 256;
    int tid = threadIdx.x;
    int lr4 = tid >> 6, lc = tid & 63;

    #pragma unroll
    for (int l = 0; l < 16; ++l) {
        int rr = l * 4 + lr4;
        T[rr][lc] = s[(size_t)(r0 + rr) * 256 + c0 + lc];
    }
    __syncthreads();
    int r = r0 + lc;
    int p = r / 49, t = r - p * 49;
    #pragma unroll
    for (int l = 0; l < 16; ++l) {
        int cc = l * 4 + lr4;
        size_t dst = (((size_t)(b * 256 + c0 + cc) * 256) + p) * 64 + t;
        pc_pad[dst] = *(unsigned short*)&T[lc][cc];
    }
    int plo = r0 / 49, phi = (r0 + 63) / 49;
    for (int pp = plo; pp <= phi; ++pp) {
        if (pp >= 256) break;
        for (int idx = tid; idx < 64 * 15; idx += 256) {
            int cc = idx / 15, t2 = 49 + idx % 15;
            size_t dst = (((size_t)(b * 256 + c0 + cc) * 256) + pp) * 64 + t2;
            pc_pad[dst] = 0;
        }
    }
}

// ---------------------------------------------------------------------------
// 6) batched 2D transpose: src[b][R][Cc] -> dst[b][Cc][R]; grid (Cc/64,R/64,B)
// ---------------------------------------------------------------------------
__global__ __launch_bounds__(256) void transpose_bf16_kernel(
    const __hip_bfloat16* __restrict__ src, __hip_bfloat16* __restrict__ dst,
    int R, int Cc)
{
    __shared__ __hip_bfloat16 T[64][66];
    int b = blockIdx.z;
    int r0 = blockIdx.y * 64, c0 = blockIdx.x * 64;
    const __hip_bfloat16* s = src + (size_t)b * R * Cc;
    __hip_bfloat16* d = dst + (size_t)b * R * Cc;
    int tid = threadIdx.x;
    int lr = tid >> 6, lc = tid & 63;

    #pragma unroll
    for (int l = 0; l < 16; ++l) {
        int rr = l * 4 + lr;
        T[rr][lc] = s[(size_t)(r0 + rr) * Cc + c0 + lc];
    }
    __syncthreads();
    #pragma unroll
    for (int l = 0; l < 16; ++l) {
        int cc = l * 4 + lr;
        d[(size_t)(c0 + cc) * R + r0 + lc] = T[lc][cc];
    }
}

// ---------------------------------------------------------------------------
__global__ void ws_marker_kernel(float* __restrict__ out0)
{
    if (threadIdx.x == 0) out0[0] = 777.0f;
}

// ---------------------------------------------------------------------------
extern "C" void kernel_launch(void* const* d_in, const int* in_sizes, int n_in,
                              void* d_out, int out_size, void* d_ws, size_t ws_size,
                              hipStream_t stream)
{
    const float* x        = (const float*)d_in[0];
    const float* gamma    = (const float*)d_in[1];
    const float* beta     = (const float*)d_in[2];
    const float* qkv_l_w  = (const float*)d_in[3];
    const float* qkv_l_b  = (const float*)d_in[4];
    const float* proj_l_w = (const float*)d_in[5];
    const float* proj_l_b = (const float*)d_in[6];
    const float* rpb      = (const float*)d_in[7];
    const float* qkv_c_w  = (const float*)d_in[8];
    const float* qkv_c_b  = (const float*)d_in[9];
    const float* proj_c_w = (const float*)d_in[10];
    const float* proj_c_b = (const float*)d_in[11];
    const float* proj_w   = (const float*)d_in[12];

    float* out0 = (float*)d_out;
    float* out1 = out0 + ELEMS;

    copy_f32_kernel<<<(int)(ELEMS / 1024), 256, 0, stream>>>(x, out1);

    char* ws = (char*)d_ws;
    if (ws_size < 6 * SZ) {
        ws_marker_kernel<<<1, 64, 0, stream>>>(out0);
        return;
    }

    const size_t P = SZ;
    // plane/lifetime map (identical to R13):
    __hip_bfloat16* localOut  = (__hip_bfloat16*)(ws + 0 * P);
    unsigned short* wt_qkv_l  = (unsigned short*)(ws + 0 * P);
    float*          biasb     = (float*)(ws + 0 * P + 0x80000);
    __hip_bfloat16* patches   = (__hip_bfloat16*)(ws + 1 * P);
    __hip_bfloat16* qkv_l     = (__hip_bfloat16*)(ws + 2 * P);
    __hip_bfloat16* attnL     = (__hip_bfloat16*)(ws + 5 * P);
    char*           G         = ws + 4 * P + 0xB00000;
    unsigned short* wt_proj_l = (unsigned short*)(G + 0x000000);
    unsigned short* wt_qkv_c  = (unsigned short*)(G + 0x080000);
    unsigned short* wt_proj_c = (unsigned short*)(G + 0x100000);
    unsigned short* wt_final  = (unsigned short*)(G + 0x180000);
    float*          biasc     = (float*)(G + 0x300000);
    __hip_bfloat16* pc_pad    = (__hip_bfloat16*)(ws + 6 * P - (size_t)262144 * 64 * 2);
    __hip_bfloat16* qkvc      = (__hip_bfloat16*)(ws + 1 * P);
    __hip_bfloat16* crossAttn = pc_pad;
    __hip_bfloat16* crossProj = (__hip_bfloat16*)(ws + 1 * P);
    __hip_bfloat16* crossT    = (__hip_bfloat16*)(ws + 2 * P);

    // K0) weight prep needed before K3; bias table before K4
    prep_wt_kernel<<<768, 256, 0, stream>>>(qkv_l_w, wt_qkv_l, 256, 768, 256, 768);
    bias_prep_kernel<<<128, 256, 0, stream>>>(rpb, biasb);
    // K1) LN + window partition
    ln_partition_kernel<<<BB * HH * 7, 256, 0, stream>>>(x, gamma, beta, patches);
    // K3) qkv_local: [50176,256] @ [256,768], pitch 768
    gemm_mfma_kernel<<<dim3(6, 392), 256, 0, stream>>>(
        patches, nullptr, 256, wt_qkv_l, qkv_l_b, qkv_l, nullptr, 50176, 768, 256, 768);
    // K4) local attention (MFMA)
    local_attn_mfma_kernel<<<1024 * NHEAD, 64, 0, stream>>>(qkv_l, biasb, attnL);
    // K4.5) remaining weight preps
    prep_wt_kernel<<<256, 256, 0, stream>>>(proj_l_w, wt_proj_l, 256, 256, 256, 256);
    prep_wt_qkvc_kernel<<<64, 256, 0, stream>>>(qkv_c_w, wt_qkv_c);
    prep_bias_c_kernel<<<1, 192, 0, stream>>>(qkv_c_b, biasc);
    prep_wt_kernel<<<32, 256, 0, stream>>>(proj_c_w, wt_proj_c, 49, 49, 64, 128);
    prep_wt_kernel<<<512, 256, 0, stream>>>(proj_w, wt_final, 512, 256, 512, 256);
    // K5) proj_local: [50176,256] @ [256,256], pitch 256
    gemm_mfma_kernel<<<dim3(2, 392), 256, 0, stream>>>(
        attnL, nullptr, 256, wt_proj_l, proj_l_b, localOut, nullptr, 50176, 256, 256, 256);
    // K6) fused transpose+pad: patches -> pc_pad [262144][64]
    transpose_pad_kernel<<<dim3(4, 196, BB), 256, 0, stream>>>(
        patches, (unsigned short*)pc_pad);
    // K7) qkv_cross: [262144,64pad] @ [64,161 remapped] -> qkvc pitch 168
    gemm_mfma_kernel<<<dim3(2, 2048), 256, 0, stream>>>(
        pc_pad, nullptr, 64, wt_qkv_c, biasc, qkvc, nullptr, 262144, 161, 64, 168);
    // K8) cross attention (reads pitch 168, aligned segments)
    cross_attn_mfma_kernel<<<1024, 256, 0, stream>>>(qkvc, crossAttn);
    // K9) proj_cross: [262144,64pad] @ [64,49] -> dense [262144][49]
    gemm_mfma_kernel<<<dim3(1, 2048), 256, 0, stream>>>(
        crossAttn, nullptr, 64, wt_proj_c, proj_c_b, crossProj, nullptr, 262144, 49, 64, 49);
    // K10) crossT = per-b transpose back
    transpose_bf16_kernel<<<dim3(196, 4, BB), 256, 0, stream>>>(crossProj, crossT, 256, 12544);
    // K11) final: concat[localOut|crossT] @ proj_w -> out0 fp32 BCHW
    gemm_mfma_kernel<<<dim3(2, 392), 256, 0, stream>>>(
        localOut, crossT, 256, wt_final, nullptr, nullptr, out0, 50176, 256, 512, 256);
}

// Round 17
// 349.285 us; speedup vs baseline: 1.1662x; 1.1662x over previous
//
#include <hip/hip_runtime.h>
#include <hip/hip_bf16.h>

// Problem geometry (fixed by the reference):
// B=4, C=256, H=W=112, ps=7, N=49, nP=256 windows/batch, NH=8, d=32.
// Inputs fp32. d_out is FP32: [out | shortcut], each (B,C,H,W).

#define PS 7
#define NWIN_N 49
#define CH 256
#define HH 112
#define WW 112
#define BB 4
#define NHEAD 8
#define HD 32

static constexpr size_t ELEMS = (size_t)BB * CH * HH * WW;      // 12,845,056
static constexpr size_t SZ    = ELEMS * 2;                      // 25,690,112 B (one bf16 plane)

typedef __attribute__((ext_vector_type(8))) short short8;
typedef __attribute__((ext_vector_type(4))) float f32x4;

static __device__ __forceinline__ unsigned short bf16_bits(float v) {
    __hip_bfloat16 h = __float2bfloat16(v);
    return *reinterpret_cast<unsigned short*>(&h);
}

// async global->LDS, 16B per lane; lptr wave-uniform, gptr per-lane.
static __device__ __forceinline__ void gload_lds16(const void* g, void* l) {
    __builtin_amdgcn_global_load_lds(
        (const __attribute__((address_space(1))) unsigned int*)g,
        (__attribute__((address_space(3))) unsigned int*)l, 16, 0, 0);
}

// ---------------------------------------------------------------------------
// 1) LayerNorm over C + window partition -> patches (bf16), FUSED shortcut
// copy (fp32 -> out1). block = (b*112+h)*7 + seg; seg = 16 w-cols; 256 thr.
// ---------------------------------------------------------------------------
__global__ __launch_bounds__(256) void ln_partition_kernel(
    const float* __restrict__ x, const float* __restrict__ gamma,
    const float* __restrict__ beta, __hip_bfloat16* __restrict__ patches,
    float* __restrict__ out1)
{
    int blk = blockIdx.x;
    int seg = blk % 7;
    int bh = blk / 7;
    int h = bh % HH, b = bh / HH;
    int w0 = seg * 16;
    int tid = threadIdx.x;

    __shared__ float X[256][17];
    __shared__ float mus[16], rstds[16];

    #pragma unroll
    for (int l = 0; l < 16; ++l) {
        int idx = l * 256 + tid;
        int c = idx >> 4, wl = idx & 15;
        size_t gi = ((size_t)(b * CH + c) * HH + h) * WW + w0 + wl;
        float v = x[gi];
        X[c][wl] = v;
        out1[gi] = v;                      // fused shortcut copy
    }
    __syncthreads();

    if (tid < 16) {
        float s = 0.f, ss = 0.f;
        for (int c = 0; c < 256; ++c) { float v = X[c][tid]; s += v; ss += v * v; }
        float mu = s * (1.f / 256.f);
        float var = ss * (1.f / 256.f) - mu * mu;
        mus[tid] = mu;
        rstds[tid] = rsqrtf(var + 1e-5f);
    }
    __syncthreads();

    int c = tid;
    float g = gamma[c], be = beta[c];
    int hp = h / PS, r = h - hp * PS;
    #pragma unroll
    for (int wl = 0; wl < 16; ++wl) {
        int w = w0 + wl;
        int wp = w / PS, cc = w - wp * PS;
        int win = (b * 16 + hp) * 16 + wp;
        int i = r * PS + cc;
        float v = (X[c][wl] - mus[wl]) * rstds[wl] * g + be;
        patches[((size_t)win * NWIN_N + i) * CH + c] = __float2bfloat16(v);
    }
}

// ---------------------------------------------------------------------------
// prep: W fp32 [Kreal][N] -> Wt bf16 [Npad][Kpad] k-major, zero padded
// ---------------------------------------------------------------------------
__global__ __launch_bounds__(256) void prep_wt_kernel(
    const float* __restrict__ W, unsigned short* __restrict__ Wt,
    int Kreal, int N, int Kpad, int Npad)
{
    int idx = blockIdx.x * 256 + threadIdx.x;
    if (idx >= Npad * Kpad) return;
    int n = idx / Kpad, k = idx - n * Kpad;
    float v = (n < N && k < Kreal) ? W[(size_t)k * N + n] : 0.f;
    Wt[idx] = bf16_bits(v);
}

// ---------------------------------------------------------------------------
// prep for qkv_cross with aligned-segment remap (q@0, k@56, v@112):
// ---------------------------------------------------------------------------
__global__ __launch_bounds__(256) void prep_wt_qkvc_kernel(
    const float* __restrict__ W, unsigned short* __restrict__ Wt)
{
    int idx = blockIdx.x * 256 + threadIdx.x;
    if (idx >= 192 * 64) return;
    int n = idx >> 6, k = idx & 63;
    int s = -1;
    if (n < 49) s = n;
    else if (n >= 56 && n < 105) s = n - 7;
    else if (n >= 112 && n < 161) s = n - 14;
    float v = (s >= 0 && k < 49) ? W[(size_t)k * 147 + s] : 0.f;
    Wt[idx] = bf16_bits(v);
}

__global__ __launch_bounds__(192) void prep_bias_c_kernel(
    const float* __restrict__ b, float* __restrict__ bc)
{
    int n = threadIdx.x;   // < 192
    int s = -1;
    if (n < 49) s = n;
    else if (n >= 56 && n < 105) s = n - 7;
    else if (n >= 112 && n < 161) s = n - 14;
    bc[n] = (s >= 0) ? b[s] : 0.f;
}

// ---------------------------------------------------------------------------
// bias prep: rpb [169][8] -> biasb[8][64][64] fp32 padded.
// ---------------------------------------------------------------------------
__global__ __launch_bounds__(256) void bias_prep_kernel(
    const float* __restrict__ rpb, float* __restrict__ biasb)
{
    int idx = blockIdx.x * 256 + threadIdx.x;   // < 32768
    int head = idx >> 12;
    int rem = idx & 4095;
    int i = rem >> 6, j = rem & 63;
    float v;
    if (j >= NWIN_N) v = -1e9f;
    else if (i >= NWIN_N) v = 0.f;
    else {
        int ri = i / 7, ci = i - ri * 7;
        int rj = j / 7, cj = j - rj * 7;
        v = rpb[((ri - rj + 6) * 13 + (ci - cj + 6)) * NHEAD + head];
    }
    biasb[idx] = v;
}

// ---------------------------------------------------------------------------
// Unified MFMA GEMM (R13 proven form): BM=128, BN=64, BK=64; 256 thr = 4
// waves (2x2); 16x16x32 MFMA. gload_lds(16B) staging, linear LDS dest +
// pre-swizzled global source + XOR reads (rule #21). XCD-chunked tile
// swizzle (all call sites have ntiles % 8 == 0).
// ---------------------------------------------------------------------------
__global__ __launch_bounds__(256) void gemm_mfma_kernel(
    const __hip_bfloat16* __restrict__ A1p, const __hip_bfloat16* __restrict__ A2p,
    int K1, const unsigned short* __restrict__ Wt, const float* __restrict__ bias,
    __hip_bfloat16* __restrict__ Cb, float* __restrict__ Cf,
    int M, int N, int K, int pitchN)
{
    __shared__ __align__(16) unsigned short Alds[128 * 64];   // 16 KB, swizzled slots
    __shared__ __align__(16) unsigned short Wlds[64 * 64];    // 8 KB
    const unsigned short* A1 = (const unsigned short*)A1p;
    const unsigned short* A2 = (const unsigned short*)A2p;

    const int nb = gridDim.x;
    const int ntiles = nb * gridDim.y;
    const int bid = blockIdx.y * nb + blockIdx.x;
    const int chunk = ntiles >> 3;
    const int tile = (bid & 7) * chunk + (bid >> 3);
    const int m0 = (tile / nb) * 128, n0 = (tile % nb) * 64;

    const int tid = threadIdx.x, lane = tid & 63, wave = tid >> 6;
    const int wm = wave >> 1, wn = wave & 1;
    const int lr = lane & 15, lk = lane >> 4;

    f32x4 acc[4][2];
    #pragma unroll
    for (int i = 0; i < 4; ++i)
        #pragma unroll
        for (int j = 0; j < 2; ++j) acc[i][j] = (f32x4){0.f, 0.f, 0.f, 0.f};

    for (int k0 = 0; k0 < K; k0 += 64) {
        #pragma unroll
        for (int i = 0; i < 4; ++i) {
            int s_lin = i * 256 + tid;
            int row = s_lin >> 3, sl = s_lin & 7;
            int c8 = ((sl ^ (row & 7)) << 3);
            int k = k0 + c8;
            const unsigned short* src = (k < K1)
                ? A1 + (size_t)(m0 + row) * K1 + k
                : A2 + (size_t)(m0 + row) * (K - K1) + (k - K1);
            gload_lds16(src, Alds + (size_t)(i * 256 + wave * 64) * 8);
        }
        #pragma unroll
        for (int i = 0; i < 2; ++i) {
            int s_lin = i * 256 + tid;
            int row = s_lin >> 3, sl = s_lin & 7;
            int c8 = ((sl ^ (row & 7)) << 3);
            gload_lds16(Wt + (size_t)(n0 + row) * K + k0 + c8,
                        Wlds + (size_t)(i * 256 + wave * 64) * 8);
        }
        __syncthreads();
        #pragma unroll
        for (int kk = 0; kk < 64; kk += 32) {
            short8 a[4], w[2];
            #pragma unroll
            for (int mi = 0; mi < 4; ++mi) {
                int r = wm * 64 + mi * 16 + lr;
                int sl = (kk >> 3) + lk;
                a[mi] = *(const short8*)&Alds[(r << 6) + (((sl) ^ (r & 7)) << 3)];
            }
            #pragma unroll
            for (int nj = 0; nj < 2; ++nj) {
                int r = wn * 32 + nj * 16 + lr;
                int sl = (kk >> 3) + lk;
                w[nj] = *(const short8*)&Wlds[(r << 6) + (((sl) ^ (r & 7)) << 3)];
            }
            #pragma unroll
            for (int mi = 0; mi < 4; ++mi)
                #pragma unroll
                for (int nj = 0; nj < 2; ++nj)
                    acc[mi][nj] = __builtin_amdgcn_mfma_f32_16x16x32_bf16(
                        a[mi], w[nj], acc[mi][nj], 0, 0, 0);
        }
        __syncthreads();
    }

    if (Cb) {
        if ((pitchN & 7) == 0) {
            #pragma unroll
            for (int nj = 0; nj < 2; ++nj) {
                int n = n0 + wn * 32 + nj * 16 + lr;
                float bv = (bias && n < N) ? bias[n] : 0.f;
                int col = wn * 32 + nj * 16 + lr;
                #pragma unroll
                for (int mi = 0; mi < 4; ++mi)
                    #pragma unroll
                    for (int r = 0; r < 4; ++r) {
                        int row = wm * 64 + mi * 16 + lk * 4 + r;
                        int idx = (row << 6) + (((col >> 3) ^ (row & 7)) << 3) + (col & 7);
                        Alds[idx] = bf16_bits(acc[mi][nj][r] + bv);
                    }
            }
            __syncthreads();
            #pragma unroll
            for (int i = 0; i < 4; ++i) {
                int s = tid + 256 * i;
                int row = s >> 3, sl = s & 7;
                if (n0 + sl * 8 + 8 <= pitchN)
                    *(short8*)((unsigned short*)Cb + (size_t)(m0 + row) * pitchN + n0 + sl * 8) =
                        *(const short8*)&Alds[(row << 6) + (((sl) ^ (row & 7)) << 3)];
            }
        } else {
            #pragma unroll
            for (int nj = 0; nj < 2; ++nj) {
                int n = n0 + wn * 32 + nj * 16 + lr;
                if (n >= N) continue;
                float bv = bias ? bias[n] : 0.f;
                #pragma unroll
                for (int mi = 0; mi < 4; ++mi) {
                    #pragma unroll
                    for (int r = 0; r < 4; ++r) {
                        int m = m0 + wm * 64 + mi * 16 + lk * 4 + r;
                        ((unsigned short*)Cb)[(size_t)m * pitchN + n] =
                            bf16_bits(acc[mi][nj][r] + bv);
                    }
                }
            }
        }
    } else {
        #pragma unroll
        for (int mi = 0; mi < 4; ++mi) {
            #pragma unroll
            for (int r = 0; r < 4; ++r) {
                int m = m0 + wm * 64 + mi * 16 + lk * 4 + r;
                int b = m / 12544, rem = m - b * 12544;
                int p = rem / 49, t = rem - p * 49;
                int h = (p >> 4) * 7 + t / 7, w = (p & 15) * 7 + (t % 7);
                size_t ob = ((size_t)(b * 256) * HH + h) * WW + w;
                #pragma unroll
                for (int nj = 0; nj < 2; ++nj) {
                    int ch = n0 + wn * 32 + nj * 16 + lr;
                    Cf[ob + (size_t)ch * (HH * WW)] = acc[mi][nj][r];
                }
            }
        }
    }
}

// ---------------------------------------------------------------------------
// 4) local windowed attention, MFMA. One wave per (win, head).
// ---------------------------------------------------------------------------
__global__ __launch_bounds__(64) void local_attn_mfma_kernel(
    const __hip_bfloat16* __restrict__ qkv,   // [50176][768] q|k|v
    const float* __restrict__ biasb,          // [8][64][64] fp32 padded
    __hip_bfloat16* __restrict__ outp)        // [50176][256]
{
    __shared__ __align__(16) unsigned short VT_lds[32][72];
    __shared__ __align__(16) unsigned short P_lds[16][72];

    const int win  = blockIdx.x >> 3;
    const int head = blockIdx.x & 7;
    const int lane = threadIdx.x;
    const int lr = lane & 15, lk = lane >> 4;
    const unsigned short* q16 = (const unsigned short*)qkv;
    const size_t rowbase = (size_t)win * NWIN_N;
    const float scale = 0.17677669529663687f;   // 32^-0.5

    for (int t = 0; t < 32; ++t) {
        int idx = lane + 64 * t;
        int j = idx >> 5, d = idx & 31;
        unsigned short v = 0;
        if (j < NWIN_N) v = q16[(rowbase + j) * 768 + 512 + head * HD + d];
        VT_lds[d][j] = v;
    }

    short8 kf[4], qf[4];
    #pragma unroll
    for (int jt = 0; jt < 4; ++jt) {
        int j = jt * 16 + lr;
        short8 f = *(const short8*)(q16 + (rowbase + j) * 768 + 256 + head * HD + lk * 8);
        if (j >= NWIN_N) {
            #pragma unroll
            for (int e = 0; e < 8; ++e) f[e] = 0;
        }
        kf[jt] = f;
    }
    #pragma unroll
    for (int it = 0; it < 4; ++it) {
        int i = it * 16 + lr;
        qf[it] = *(const short8*)(q16 + (rowbase + i) * 768 + head * HD + lk * 8);
    }
    __syncthreads();

    #pragma unroll
    for (int it = 0; it < 4; ++it) {
        const int i = it * 16 + lr;
        f32x4 sacc[4];
        #pragma unroll
        for (int jt = 0; jt < 4; ++jt) {
            f32x4 z = (f32x4){0.f, 0.f, 0.f, 0.f};
            sacc[jt] = __builtin_amdgcn_mfma_f32_16x16x32_bf16(kf[jt], qf[it], z, 0, 0, 0);
        }
        const float* brow = biasb + head * 4096 + i * 64;
        float sv[4][4];
        float mt = -1e30f;
        #pragma unroll
        for (int jt = 0; jt < 4; ++jt) {
            float4 bv = *(const float4*)&brow[jt * 16 + lk * 4];
            sv[jt][0] = sacc[jt][0] * scale + bv.x;
            sv[jt][1] = sacc[jt][1] * scale + bv.y;
            sv[jt][2] = sacc[jt][2] * scale + bv.z;
            sv[jt][3] = sacc[jt][3] * scale + bv.w;
            #pragma unroll
            for (int r = 0; r < 4; ++r) mt = fmaxf(mt, sv[jt][r]);
        }
        mt = fmaxf(mt, __shfl_xor(mt, 16, 64));
        mt = fmaxf(mt, __shfl_xor(mt, 32, 64));
        float psum = 0.f;
        #pragma unroll
        for (int jt = 0; jt < 4; ++jt) {
            float p0 = __expf(sv[jt][0] - mt);
            float p1 = __expf(sv[jt][1] - mt);
            float p2 = __expf(sv[jt][2] - mt);
            float p3 = __expf(sv[jt][3] - mt);
            psum += (p0 + p1) + (p2 + p3);
            uint2 wv;
            wv.x = (unsigned)bf16_bits(p0) | ((unsigned)bf16_bits(p1) << 16);
            wv.y = (unsigned)bf16_bits(p2) | ((unsigned)bf16_bits(p3) << 16);
            *(uint2*)&P_lds[lr][jt * 16 + lk * 4] = wv;
        }
        psum += __shfl_xor(psum, 16, 64);
        psum += __shfl_xor(psum, 32, 64);
        __syncthreads();

        f32x4 oacc[2];
        oacc[0] = (f32x4){0.f, 0.f, 0.f, 0.f};
        oacc[1] = (f32x4){0.f, 0.f, 0.f, 0.f};
        #pragma unroll
        for (int kst = 0; kst < 2; ++kst) {
            short8 bfv = *(const short8*)&P_lds[lr][kst * 32 + lk * 8];
            #pragma unroll
            for (int dt = 0; dt < 2; ++dt) {
                short8 af = *(const short8*)&VT_lds[dt * 16 + lr][kst * 32 + lk * 8];
                oacc[dt] = __builtin_amdgcn_mfma_f32_16x16x32_bf16(af, bfv, oacc[dt], 0, 0, 0);
            }
        }
        if (i < NWIN_N) {
            float inv = 1.f / psum;
            unsigned short* orow = (unsigned short*)outp + (rowbase + i) * CH + head * HD;
            #pragma unroll
            for (int dt = 0; dt < 2; ++dt) {
                uint2 wv;
                wv.x = (unsigned)bf16_bits(oacc[dt][0] * inv)
                     | ((unsigned)bf16_bits(oacc[dt][1] * inv) << 16);
                wv.y = (unsigned)bf16_bits(oacc[dt][2] * inv)
                     | ((unsigned)bf16_bits(oacc[dt][3] * inv) << 16);
                *(uint2*)&orow[dt * 16 + lk * 4] = wv;
            }
        }
        __syncthreads();
    }
}

// ---------------------------------------------------------------------------
// 5) cross-channel attention, MFMA flash. qkvc pitch 168: q@0, k@56, v@112.
// ---------------------------------------------------------------------------
__global__ __launch_bounds__(256) void cross_attn_mfma_kernel(
    const __hip_bfloat16* __restrict__ qkv,   // [262144][168]
    __hip_bfloat16* __restrict__ outp)        // [262144][64] padded
{
    __shared__ __align__(16) unsigned short K_lds[64][72];
    __shared__ __align__(16) unsigned short VT_lds[64][72];
    __shared__ __align__(16) unsigned short P_lds[2][64][72]; // [0] doubles as V-scratch

    const int bc = blockIdx.x;
    const size_t base = (size_t)bc * 256;
    const int tid  = threadIdx.x;
    const int lane = tid & 63;
    const int wave = tid >> 6;
    const int i0w  = wave * 64;
    const int lr   = lane & 15;
    const int lk   = lane >> 4;
    const int prow = wave * 16 + lr;

    const unsigned short* q16 = (const unsigned short*)qkv;
    const float inv7 = 1.f / 7.f;   // 49^-0.5
    const short8 zf = (short8){0, 0, 0, 0, 0, 0, 0, 0};

    short8 qf[4][2];
    #pragma unroll
    for (int it = 0; it < 4; ++it) {
        const unsigned short* qrow = q16 + (base + i0w + it * 16 + lr) * 168;
        #pragma unroll
        for (int kst = 0; kst < 2; ++kst) {
            int k0 = lk * 8 + kst * 32;
            qf[it][kst] = (k0 <= 48) ? *(const short8*)(qrow + k0) : zf;
        }
    }

    float m_run[4], l_run[4];
    f32x4 acc_o[4][4];   // [dt][it]
    #pragma unroll
    for (int it = 0; it < 4; ++it) { m_run[it] = -1e30f; l_run[it] = 0.f; }
    #pragma unroll
    for (int dt = 0; dt < 4; ++dt)
        #pragma unroll
        for (int it = 0; it < 4; ++it) acc_o[dt][it] = (f32x4){0.f, 0.f, 0.f, 0.f};

    for (int jt4 = 0; jt4 < 4; ++jt4) {
        const int j0 = jt4 * 64;
        {
            const int jr = tid >> 3, c8 = (tid & 7) * 8;
            #pragma unroll
            for (int h = 0; h < 2; ++h) {
                int jj = jr + h * 32;
                const unsigned short* row = q16 + (base + j0 + jj) * 168;
                *(short8*)&K_lds[jj][c8]    = (c8 <= 48) ? *(const short8*)(row + 56 + c8) : zf;
                *(short8*)&P_lds[0][jj][c8] = (c8 <= 48) ? *(const short8*)(row + 112 + c8) : zf;
            }
        }
        __syncthreads();
        {
            const int jj = tid & 63, dg = tid >> 6;
            #pragma unroll
            for (int e = 0; e < 16; ++e) {
                int d = dg * 16 + e;
                VT_lds[d][jj] = P_lds[0][jj][d];
            }
        }
        __syncthreads();

        #pragma unroll
        for (int it = 0; it < 4; ++it) {
            unsigned short* prowp = &P_lds[it & 1][prow][0];
            f32x4 sacc[4];
            #pragma unroll
            for (int jt = 0; jt < 4; ++jt) sacc[jt] = (f32x4){0.f, 0.f, 0.f, 0.f};
            #pragma unroll
            for (int kst = 0; kst < 2; ++kst) {
                #pragma unroll
                for (int jt = 0; jt < 4; ++jt) {
                    short8 af = *(const short8*)&K_lds[jt * 16 + lr][lk * 8 + kst * 32];
                    sacc[jt] = __builtin_amdgcn_mfma_f32_16x16x32_bf16(
                        af, qf[it][kst], sacc[jt], 0, 0, 0);
                }
            }
            float mt = -1e30f;
            #pragma unroll
            for (int jt = 0; jt < 4; ++jt)
                #pragma unroll
                for (int r = 0; r < 4; ++r) mt = fmaxf(mt, sacc[jt][r]);
            mt = fmaxf(mt, __shfl_xor(mt, 16, 64));
            mt = fmaxf(mt, __shfl_xor(mt, 32, 64));
            float mnew = fmaxf(m_run[it], mt * inv7);
            float corr = __expf(m_run[it] - mnew);
            m_run[it] = mnew;
            l_run[it] *= corr;
            #pragma unroll
            for (int dt = 0; dt < 4; ++dt)
                #pragma unroll
                for (int r = 0; r < 4; ++r) acc_o[dt][it][r] *= corr;

            float psum = 0.f;
            #pragma unroll
            for (int jt = 0; jt < 4; ++jt) {
                float p0 = __expf(sacc[jt][0] * inv7 - mnew);
                float p1 = __expf(sacc[jt][1] * inv7 - mnew);
                float p2 = __expf(sacc[jt][2] * inv7 - mnew);
                float p3 = __expf(sacc[jt][3] * inv7 - mnew);
                psum += (p0 + p1) + (p2 + p3);
                uint2 wv;
                wv.x = (unsigned)bf16_bits(p0) | ((unsigned)bf16_bits(p1) << 16);
                wv.y = (unsigned)bf16_bits(p2) | ((unsigned)bf16_bits(p3) << 16);
                *(uint2*)(prowp + jt * 16 + lk * 4) = wv;
            }
            psum += __shfl_xor(psum, 16, 64);
            psum += __shfl_xor(psum, 32, 64);
            l_run[it] += psum;

            #pragma unroll
            for (int kst = 0; kst < 2; ++kst) {
                short8 bfv = *(const short8*)(prowp + kst * 32 + lk * 8);
                #pragma unroll
                for (int dt = 0; dt < 4; ++dt) {
                    short8 af = *(const short8*)&VT_lds[dt * 16 + lr][kst * 32 + lk * 8];
                    acc_o[dt][it] = __builtin_amdgcn_mfma_f32_16x16x32_bf16(
                        af, bfv, acc_o[dt][it], 0, 0, 0);
                }
            }
        }
        __syncthreads();
    }

    #pragma unroll
    for (int it = 0; it < 4; ++it) {
        float inv = 1.f / l_run[it];
        unsigned short* orow = (unsigned short*)outp + (base + i0w + it * 16 + lr) * 64;
        #pragma unroll
        for (int dt = 0; dt < 4; ++dt) {
            uint2 wv;
            wv.x = (unsigned)bf16_bits(acc_o[dt][it][0] * inv)
                 | ((unsigned)bf16_bits(acc_o[dt][it][1] * inv) << 16);
            wv.y = (unsigned)bf16_bits(acc_o[dt][it][2] * inv)
                 | ((unsigned)bf16_bits(acc_o[dt][it][3] * inv) << 16);
            *(uint2*)&orow[dt * 16 + lk * 4] = wv;
        }
    }
}

// ---------------------------------------------------------------------------
// 6a) FUSED transpose + pad: patches -> pc_pad[((b*256+c)*256+p)*64+t]
// ---------------------------------------------------------------------------
__global__ __launch_bounds__(256) void transpose_pad_kernel(
    const __hip_bfloat16* __restrict__ patches, unsigned short* __restrict__ pc_pad)
{
    __shared__ __hip_bfloat16 T[64][66];
    int b = blockIdx.z;
    int r0 = blockIdx.y * 64, c0 = blockIdx.x * 64;
    const __hip_bfloat16* s = patches + (size_t)b * 12544 * 256;
    int tid = threadIdx.x;
    int lr4 = tid >> 6, lc = tid & 63;

    #pragma unroll
    for (int l = 0; l < 16; ++l) {
        int rr = l * 4 + lr4;
        T[rr][lc] = s[(size_t)(r0 + rr) * 256 + c0 + lc];
    }
    __syncthreads();
    int r = r0 + lc;
    int p = r / 49, t = r - p * 49;
    #pragma unroll
    for (int l = 0; l < 16; ++l) {
        int cc = l * 4 + lr4;
        size_t dst = (((size_t)(b * 256 + c0 + cc) * 256) + p) * 64 + t;
        pc_pad[dst] = *(unsigned short*)&T[lc][cc];
    }
    int plo = r0 / 49, phi = (r0 + 63) / 49;
    for (int pp = plo; pp <= phi; ++pp) {
        if (pp >= 256) break;
        for (int idx = tid; idx < 64 * 15; idx += 256) {
            int cc = idx / 15, t2 = 49 + idx % 15;
            size_t dst = (((size_t)(b * 256 + c0 + cc) * 256) + pp) * 64 + t2;
            pc_pad[dst] = 0;
        }
    }
}

// ---------------------------------------------------------------------------
// 6) batched 2D transpose: src[b][R][Cc] -> dst[b][Cc][R]; grid (Cc/64,R/64,B)
// ---------------------------------------------------------------------------
__global__ __launch_bounds__(256) void transpose_bf16_kernel(
    const __hip_bfloat16* __restrict__ src, __hip_bfloat16* __restrict__ dst,
    int R, int Cc)
{
    __shared__ __hip_bfloat16 T[64][66];
    int b = blockIdx.z;
    int r0 = blockIdx.y * 64, c0 = blockIdx.x * 64;
    const __hip_bfloat16* s = src + (size_t)b * R * Cc;
    __hip_bfloat16* d = dst + (size_t)b * R * Cc;
    int tid = threadIdx.x;
    int lr = tid >> 6, lc = tid & 63;

    #pragma unroll
    for (int l = 0; l < 16; ++l) {
        int rr = l * 4 + lr;
        T[rr][lc] = s[(size_t)(r0 + rr) * Cc + c0 + lc];
    }
    __syncthreads();
    #pragma unroll
    for (int l = 0; l < 16; ++l) {
        int cc = l * 4 + lr;
        d[(size_t)(c0 + cc) * R + r0 + lc] = T[lc][cc];
    }
}

// ---------------------------------------------------------------------------
__global__ void ws_marker_kernel(float* __restrict__ out0)
{
    if (threadIdx.x == 0) out0[0] = 777.0f;
}

// ---------------------------------------------------------------------------
extern "C" void kernel_launch(void* const* d_in, const int* in_sizes, int n_in,
                              void* d_out, int out_size, void* d_ws, size_t ws_size,
                              hipStream_t stream)
{
    const float* x        = (const float*)d_in[0];
    const float* gamma    = (const float*)d_in[1];
    const float* beta     = (const float*)d_in[2];
    const float* qkv_l_w  = (const float*)d_in[3];
    const float* qkv_l_b  = (const float*)d_in[4];
    const float* proj_l_w = (const float*)d_in[5];
    const float* proj_l_b = (const float*)d_in[6];
    const float* rpb      = (const float*)d_in[7];
    const float* qkv_c_w  = (const float*)d_in[8];
    const float* qkv_c_b  = (const float*)d_in[9];
    const float* proj_c_w = (const float*)d_in[10];
    const float* proj_c_b = (const float*)d_in[11];
    const float* proj_w   = (const float*)d_in[12];

    float* out0 = (float*)d_out;
    float* out1 = out0 + ELEMS;

    char* ws = (char*)d_ws;
    if (ws_size < 6 * SZ) {
        ws_marker_kernel<<<1, 64, 0, stream>>>(out0);
        return;
    }

    const size_t P = SZ;
    // plane/lifetime map (identical to R13):
    __hip_bfloat16* localOut  = (__hip_bfloat16*)(ws + 0 * P);
    unsigned short* wt_qkv_l  = (unsigned short*)(ws + 0 * P);
    float*          biasb     = (float*)(ws + 0 * P + 0x80000);
    __hip_bfloat16* patches   = (__hip_bfloat16*)(ws + 1 * P);
    __hip_bfloat16* qkv_l     = (__hip_bfloat16*)(ws + 2 * P);
    __hip_bfloat16* attnL     = (__hip_bfloat16*)(ws + 5 * P);
    char*           G         = ws + 4 * P + 0xB00000;
    unsigned short* wt_proj_l = (unsigned short*)(G + 0x000000);
    unsigned short* wt_qkv_c  = (unsigned short*)(G + 0x080000);
    unsigned short* wt_proj_c = (unsigned short*)(G + 0x100000);
    unsigned short* wt_final  = (unsigned short*)(G + 0x180000);
    float*          biasc     = (float*)(G + 0x300000);
    __hip_bfloat16* pc_pad    = (__hip_bfloat16*)(ws + 6 * P - (size_t)262144 * 64 * 2);
    __hip_bfloat16* qkvc      = (__hip_bfloat16*)(ws + 1 * P);
    __hip_bfloat16* crossAttn = pc_pad;
    __hip_bfloat16* crossProj = (__hip_bfloat16*)(ws + 1 * P);
    __hip_bfloat16* crossT    = (__hip_bfloat16*)(ws + 2 * P);

    // K0) weight prep needed before K3; bias table before K4
    prep_wt_kernel<<<768, 256, 0, stream>>>(qkv_l_w, wt_qkv_l, 256, 768, 256, 768);
    bias_prep_kernel<<<128, 256, 0, stream>>>(rpb, biasb);
    // K1) LN + window partition + fused shortcut copy
    ln_partition_kernel<<<BB * HH * 7, 256, 0, stream>>>(x, gamma, beta, patches, out1);
    // K3) qkv_local: [50176,256] @ [256,768], pitch 768
    gemm_mfma_kernel<<<dim3(12, 392), 256, 0, stream>>>(
        patches, nullptr, 256, wt_qkv_l, qkv_l_b, qkv_l, nullptr, 50176, 768, 256, 768);
    // K4) local attention (MFMA)
    local_attn_mfma_kernel<<<1024 * NHEAD, 64, 0, stream>>>(qkv_l, biasb, attnL);
    // K4.5) remaining weight preps
    prep_wt_kernel<<<256, 256, 0, stream>>>(proj_l_w, wt_proj_l, 256, 256, 256, 256);
    prep_wt_qkvc_kernel<<<48, 256, 0, stream>>>(qkv_c_w, wt_qkv_c);
    prep_bias_c_kernel<<<1, 192, 0, stream>>>(qkv_c_b, biasc);
    prep_wt_kernel<<<16, 256, 0, stream>>>(proj_c_w, wt_proj_c, 49, 49, 64, 64);
    prep_wt_kernel<<<512, 256, 0, stream>>>(proj_w, wt_final, 512, 256, 512, 256);
    // K5) proj_local: [50176,256] @ [256,256], pitch 256
    gemm_mfma_kernel<<<dim3(4, 392), 256, 0, stream>>>(
        attnL, nullptr, 256, wt_proj_l, proj_l_b, localOut, nullptr, 50176, 256, 256, 256);
    // K6) fused transpose+pad: patches -> pc_pad [262144][64]
    transpose_pad_kernel<<<dim3(4, 196, BB), 256, 0, stream>>>(
        patches, (unsigned short*)pc_pad);
    // K7) qkv_cross: [262144,64pad] @ [64,161 remapped] -> qkvc pitch 168
    gemm_mfma_kernel<<<dim3(3, 2048), 256, 0, stream>>>(
        pc_pad, nullptr, 64, wt_qkv_c, biasc, qkvc, nullptr, 262144, 161, 64, 168);
    // K8) cross attention (reads pitch 168, aligned segments)
    cross_attn_mfma_kernel<<<1024, 256, 0, stream>>>(qkvc, crossAttn);
    // K9) proj_cross: [262144,64pad] @ [64,49] -> dense [262144][49]
    gemm_mfma_kernel<<<dim3(1, 2048), 256, 0, stream>>>(
        crossAttn, nullptr, 64, wt_proj_c, proj_c_b, crossProj, nullptr, 262144, 49, 64, 49);
    // K10) crossT = per-b transpose back
    transpose_bf16_kernel<<<dim3(196, 4, BB), 256, 0, stream>>>(crossProj, crossT, 256, 12544);
    // K11) final: concat[localOut|crossT] @ proj_w -> out0 fp32 BCHW
    gemm_mfma_kernel<<<dim3(4, 392), 256, 0, stream>>>(
        localOut, crossT, 256, wt_final, nullptr, nullptr, out0, 50176, 256, 512, 256);
}

// Round 19
// 332.363 us; speedup vs baseline: 1.2256x; 1.0509x over previous
//
#include <hip/hip_runtime.h>
#include <hip/hip_bf16.h>

// Problem geometry (fixed by the reference):
// B=4, C=256, H=W=112, ps=7, N=49, nP=256 windows/batch, NH=8, d=32.
// Inputs fp32. d_out is FP32: [out | shortcut], each (B,C,H,W).

#define PS 7
#define NWIN_N 49
#define CH 256
#define HH 112
#define WW 112
#define BB 4
#define NHEAD 8
#define HD 32

static constexpr size_t ELEMS = (size_t)BB * CH * HH * WW;      // 12,845,056
static constexpr size_t SZ    = ELEMS * 2;                      // 25,690,112 B (one bf16 plane)

typedef __attribute__((ext_vector_type(8))) short short8;
typedef __attribute__((ext_vector_type(4))) float f32x4;

static __device__ __forceinline__ unsigned short bf16_bits(float v) {
    __hip_bfloat16 h = __float2bfloat16(v);
    return *reinterpret_cast<unsigned short*>(&h);
}

// async global->LDS, 16B per lane; lptr wave-uniform, gptr per-lane.
static __device__ __forceinline__ void gload_lds16(const void* g, void* l) {
    __builtin_amdgcn_global_load_lds(
        (const __attribute__((address_space(1))) unsigned int*)g,
        (__attribute__((address_space(3))) unsigned int*)l, 16, 0, 0);
}

// ---------------------------------------------------------------------------
// 1) LayerNorm over C + window partition -> patches[(b*256+p)*49+i][c] (bf16)
// ---------------------------------------------------------------------------
__global__ __launch_bounds__(256) void ln_partition_kernel(
    const float* __restrict__ x, const float* __restrict__ gamma,
    const float* __restrict__ beta, __hip_bfloat16* __restrict__ patches)
{
    int blk = blockIdx.x;
    int seg = blk % 7;
    int bh = blk / 7;
    int h = bh % HH, b = bh / HH;
    int w0 = seg * 16;
    int tid = threadIdx.x;

    __shared__ float X[256][17];
    __shared__ float mus[16], rstds[16];

    #pragma unroll
    for (int l = 0; l < 16; ++l) {
        int idx = l * 256 + tid;
        int c = idx >> 4, wl = idx & 15;
        X[c][wl] = x[((size_t)(b * CH + c) * HH + h) * WW + w0 + wl];
    }
    __syncthreads();

    if (tid < 16) {
        float s = 0.f, ss = 0.f;
        for (int c = 0; c < 256; ++c) { float v = X[c][tid]; s += v; ss += v * v; }
        float mu = s * (1.f / 256.f);
        float var = ss * (1.f / 256.f) - mu * mu;
        mus[tid] = mu;
        rstds[tid] = rsqrtf(var + 1e-5f);
    }
    __syncthreads();

    int c = tid;
    float g = gamma[c], be = beta[c];
    int hp = h / PS, r = h - hp * PS;
    #pragma unroll
    for (int wl = 0; wl < 16; ++wl) {
        int w = w0 + wl;
        int wp = w / PS, cc = w - wp * PS;
        int win = (b * 16 + hp) * 16 + wp;
        int i = r * PS + cc;
        float v = (X[c][wl] - mus[wl]) * rstds[wl] * g + be;
        patches[((size_t)win * NWIN_N + i) * CH + c] = __float2bfloat16(v);
    }
}

// ---------------------------------------------------------------------------
// 2) shortcut: fp32 -> fp32 copy (float4)
// ---------------------------------------------------------------------------
__global__ __launch_bounds__(256) void copy_f32_kernel(
    const float* __restrict__ x, float* __restrict__ out)
{
    size_t i = ((size_t)blockIdx.x * 256 + threadIdx.x) * 4;
    *(float4*)(out + i) = *(const float4*)(x + i);
}

// ---------------------------------------------------------------------------
// Combined prep A (launched before K3): wt_qkv_l (768 blocks) + biasb (128).
// ---------------------------------------------------------------------------
__global__ __launch_bounds__(256) void prep_a_kernel(
    const float* __restrict__ qkv_l_w, unsigned short* __restrict__ wt_qkv_l,
    const float* __restrict__ rpb, float* __restrict__ biasb)
{
    int b = blockIdx.x;
    if (b < 768) {
        int idx = b * 256 + threadIdx.x;          // Kpad=256, Npad=768, full
        int n = idx >> 8, k = idx & 255;
        wt_qkv_l[idx] = bf16_bits(qkv_l_w[(size_t)k * 768 + n]);
    } else {
        int idx = (b - 768) * 256 + threadIdx.x;  // < 32768
        int head = idx >> 12;
        int rem = idx & 4095;
        int i = rem >> 6, j = rem & 63;
        float v;
        if (j >= NWIN_N) v = -1e9f;
        else if (i >= NWIN_N) v = 0.f;
        else {
            int ri = i / 7, ci = i - ri * 7;
            int rj = j / 7, cj = j - rj * 7;
            v = rpb[((ri - rj + 6) * 13 + (ci - cj + 6)) * NHEAD + head];
        }
        biasb[idx] = v;
    }
}

// ---------------------------------------------------------------------------
// Combined prep B (launched after K4, G region free): wt_proj_l [0,256) +
// wt_qkv_c remap [256,304) + biasc {304} + wt_proj_c [305,321) +
// wt_final [321,833).
// ---------------------------------------------------------------------------
__global__ __launch_bounds__(256) void prep_b_kernel(
    const float* __restrict__ proj_l_w, unsigned short* __restrict__ wt_proj_l,
    const float* __restrict__ qkv_c_w, unsigned short* __restrict__ wt_qkv_c,
    const float* __restrict__ qkv_c_b, float* __restrict__ biasc,
    const float* __restrict__ proj_c_w, unsigned short* __restrict__ wt_proj_c,
    const float* __restrict__ proj_w, unsigned short* __restrict__ wt_final)
{
    int b = blockIdx.x;
    int t = threadIdx.x;
    if (b < 256) {
        int idx = b * 256 + t;                    // Kpad=256, Npad=256, full
        int n = idx >> 8, k = idx & 255;
        wt_proj_l[idx] = bf16_bits(proj_l_w[(size_t)k * 256 + n]);
    } else if (b < 304) {
        int idx = (b - 256) * 256 + t;            // < 12288 = 192*64
        int n = idx >> 6, k = idx & 63;
        int s = -1;
        if (n < 49) s = n;
        else if (n >= 56 && n < 105) s = n - 7;
        else if (n >= 112 && n < 161) s = n - 14;
        float v = (s >= 0 && k < 49) ? qkv_c_w[(size_t)k * 147 + s] : 0.f;
        wt_qkv_c[idx] = bf16_bits(v);
    } else if (b == 304) {
        if (t < 192) {
            int n = t, s = -1;
            if (n < 49) s = n;
            else if (n >= 56 && n < 105) s = n - 7;
            else if (n >= 112 && n < 161) s = n - 14;
            biasc[n] = (s >= 0) ? qkv_c_b[s] : 0.f;
        }
    } else if (b < 321) {
        int idx = (b - 305) * 256 + t;            // < 4096 = 64*64
        int n = idx >> 6, k = idx & 63;
        float v = (n < 49 && k < 49) ? proj_c_w[(size_t)k * 49 + n] : 0.f;
        wt_proj_c[idx] = bf16_bits(v);
    } else {
        int idx = (b - 321) * 256 + t;            // < 131072; Kpad=512, Npad=256
        int n = idx >> 9, k = idx & 511;
        wt_final[idx] = bf16_bits(proj_w[(size_t)k * 256 + n]);
    }
}

// ---------------------------------------------------------------------------
// Unified MFMA GEMM (R13 proven form): BM=128, BN=64, BK=64; 256 thr = 4
// waves (2x2); 16x16x32 MFMA. gload_lds(16B) staging, linear LDS dest +
// pre-swizzled global source + XOR reads (rule #21). XCD-chunked tile
// swizzle (all call sites have ntiles % 8 == 0).
// ---------------------------------------------------------------------------
__global__ __launch_bounds__(256) void gemm_mfma_kernel(
    const __hip_bfloat16* __restrict__ A1p, const __hip_bfloat16* __restrict__ A2p,
    int K1, const unsigned short* __restrict__ Wt, const float* __restrict__ bias,
    __hip_bfloat16* __restrict__ Cb, float* __restrict__ Cf,
    int M, int N, int K, int pitchN)
{
    __shared__ __align__(16) unsigned short Alds[128 * 64];   // 16 KB, swizzled slots
    __shared__ __align__(16) unsigned short Wlds[64 * 64];    // 8 KB
    const unsigned short* A1 = (const unsigned short*)A1p;
    const unsigned short* A2 = (const unsigned short*)A2p;

    const int nb = gridDim.x;
    const int ntiles = nb * gridDim.y;
    const int bid = blockIdx.y * nb + blockIdx.x;
    const int chunk = ntiles >> 3;
    const int tile = (bid & 7) * chunk + (bid >> 3);
    const int m0 = (tile / nb) * 128, n0 = (tile % nb) * 64;

    const int tid = threadIdx.x, lane = tid & 63, wave = tid >> 6;
    const int wm = wave >> 1, wn = wave & 1;
    const int lr = lane & 15, lk = lane >> 4;

    f32x4 acc[4][2];
    #pragma unroll
    for (int i = 0; i < 4; ++i)
        #pragma unroll
        for (int j = 0; j < 2; ++j) acc[i][j] = (f32x4){0.f, 0.f, 0.f, 0.f};

    for (int k0 = 0; k0 < K; k0 += 64) {
        #pragma unroll
        for (int i = 0; i < 4; ++i) {
            int s_lin = i * 256 + tid;
            int row = s_lin >> 3, sl = s_lin & 7;
            int c8 = ((sl ^ (row & 7)) << 3);
            int k = k0 + c8;
            const unsigned short* src = (k < K1)
                ? A1 + (size_t)(m0 + row) * K1 + k
                : A2 + (size_t)(m0 + row) * (K - K1) + (k - K1);
            gload_lds16(src, Alds + (size_t)(i * 256 + wave * 64) * 8);
        }
        #pragma unroll
        for (int i = 0; i < 2; ++i) {
            int s_lin = i * 256 + tid;
            int row = s_lin >> 3, sl = s_lin & 7;
            int c8 = ((sl ^ (row & 7)) << 3);
            gload_lds16(Wt + (size_t)(n0 + row) * K + k0 + c8,
                        Wlds + (size_t)(i * 256 + wave * 64) * 8);
        }
        __syncthreads();
        #pragma unroll
        for (int kk = 0; kk < 64; kk += 32) {
            short8 a[4], w[2];
            #pragma unroll
            for (int mi = 0; mi < 4; ++mi) {
                int r = wm * 64 + mi * 16 + lr;
                int sl = (kk >> 3) + lk;
                a[mi] = *(const short8*)&Alds[(r << 6) + (((sl) ^ (r & 7)) << 3)];
            }
            #pragma unroll
            for (int nj = 0; nj < 2; ++nj) {
                int r = wn * 32 + nj * 16 + lr;
                int sl = (kk >> 3) + lk;
                w[nj] = *(const short8*)&Wlds[(r << 6) + (((sl) ^ (r & 7)) << 3)];
            }
            #pragma unroll
            for (int mi = 0; mi < 4; ++mi)
                #pragma unroll
                for (int nj = 0; nj < 2; ++nj)
                    acc[mi][nj] = __builtin_amdgcn_mfma_f32_16x16x32_bf16(
                        a[mi], w[nj], acc[mi][nj], 0, 0, 0);
        }
        __syncthreads();
    }

    if (Cb) {
        if ((pitchN & 7) == 0) {
            #pragma unroll
            for (int nj = 0; nj < 2; ++nj) {
                int n = n0 + wn * 32 + nj * 16 + lr;
                float bv = (bias && n < N) ? bias[n] : 0.f;
                int col = wn * 32 + nj * 16 + lr;
                #pragma unroll
                for (int mi = 0; mi < 4; ++mi)
                    #pragma unroll
                    for (int r = 0; r < 4; ++r) {
                        int row = wm * 64 + mi * 16 + lk * 4 + r;
                        int idx = (row << 6) + (((col >> 3) ^ (row & 7)) << 3) + (col & 7);
                        Alds[idx] = bf16_bits(acc[mi][nj][r] + bv);
                    }
            }
            __syncthreads();
            #pragma unroll
            for (int i = 0; i < 4; ++i) {
                int s = tid + 256 * i;
                int row = s >> 3, sl = s & 7;
                if (n0 + sl * 8 + 8 <= pitchN)
                    *(short8*)((unsigned short*)Cb + (size_t)(m0 + row) * pitchN + n0 + sl * 8) =
                        *(const short8*)&Alds[(row << 6) + (((sl) ^ (row & 7)) << 3)];
            }
        } else {
            #pragma unroll
            for (int nj = 0; nj < 2; ++nj) {
                int n = n0 + wn * 32 + nj * 16 + lr;
                if (n >= N) continue;
                float bv = bias ? bias[n] : 0.f;
                #pragma unroll
                for (int mi = 0; mi < 4; ++mi) {
                    #pragma unroll
                    for (int r = 0; r < 4; ++r) {
                        int m = m0 + wm * 64 + mi * 16 + lk * 4 + r;
                        ((unsigned short*)Cb)[(size_t)m * pitchN + n] =
                            bf16_bits(acc[mi][nj][r] + bv);
                    }
                }
            }
        }
    } else {
        #pragma unroll
        for (int mi = 0; mi < 4; ++mi) {
            #pragma unroll
            for (int r = 0; r < 4; ++r) {
                int m = m0 + wm * 64 + mi * 16 + lk * 4 + r;
                int b = m / 12544, rem = m - b * 12544;
                int p = rem / 49, t = rem - p * 49;
                int h = (p >> 4) * 7 + t / 7, w = (p & 15) * 7 + (t % 7);
                size_t ob = ((size_t)(b * 256) * HH + h) * WW + w;
                #pragma unroll
                for (int nj = 0; nj < 2; ++nj) {
                    int ch = n0 + wn * 32 + nj * 16 + lr;
                    Cf[ob + (size_t)ch * (HH * WW)] = acc[mi][nj][r];
                }
            }
        }
    }
}

// ---------------------------------------------------------------------------
// 4) local windowed attention, MFMA. One wave per (win, head).
// ---------------------------------------------------------------------------
__global__ __launch_bounds__(64) void local_attn_mfma_kernel(
    const __hip_bfloat16* __restrict__ qkv,   // [50176][768] q|k|v
    const float* __restrict__ biasb,          // [8][64][64] fp32 padded
    __hip_bfloat16* __restrict__ outp)        // [50176][256]
{
    __shared__ __align__(16) unsigned short VT_lds[32][72];
    __shared__ __align__(16) unsigned short P_lds[16][72];

    const int win  = blockIdx.x >> 3;
    const int head = blockIdx.x & 7;
    const int lane = threadIdx.x;
    const int lr = lane & 15, lk = lane >> 4;
    const unsigned short* q16 = (const unsigned short*)qkv;
    const size_t rowbase = (size_t)win * NWIN_N;
    const float scale = 0.17677669529663687f;   // 32^-0.5

    for (int t = 0; t < 32; ++t) {
        int idx = lane + 64 * t;
        int j = idx >> 5, d = idx & 31;
        unsigned short v = 0;
        if (j < NWIN_N) v = q16[(rowbase + j) * 768 + 512 + head * HD + d];
        VT_lds[d][j] = v;
    }

    short8 kf[4], qf[4];
    #pragma unroll
    for (int jt = 0; jt < 4; ++jt) {
        int j = jt * 16 + lr;
        short8 f = *(const short8*)(q16 + (rowbase + j) * 768 + 256 + head * HD + lk * 8);
        if (j >= NWIN_N) {
            #pragma unroll
            for (int e = 0; e < 8; ++e) f[e] = 0;
        }
        kf[jt] = f;
    }
    #pragma unroll
    for (int it = 0; it < 4; ++it) {
        int i = it * 16 + lr;
        qf[it] = *(const short8*)(q16 + (rowbase + i) * 768 + head * HD + lk * 8);
    }
    __syncthreads();

    #pragma unroll
    for (int it = 0; it < 4; ++it) {
        const int i = it * 16 + lr;
        f32x4 sacc[4];
        #pragma unroll
        for (int jt = 0; jt < 4; ++jt) {
            f32x4 z = (f32x4){0.f, 0.f, 0.f, 0.f};
            sacc[jt] = __builtin_amdgcn_mfma_f32_16x16x32_bf16(kf[jt], qf[it], z, 0, 0, 0);
        }
        const float* brow = biasb + head * 4096 + i * 64;
        float sv[4][4];
        float mt = -1e30f;
        #pragma unroll
        for (int jt = 0; jt < 4; ++jt) {
            float4 bv = *(const float4*)&brow[jt * 16 + lk * 4];
            sv[jt][0] = sacc[jt][0] * scale + bv.x;
            sv[jt][1] = sacc[jt][1] * scale + bv.y;
            sv[jt][2] = sacc[jt][2] * scale + bv.z;
            sv[jt][3] = sacc[jt][3] * scale + bv.w;
            #pragma unroll
            for (int r = 0; r < 4; ++r) mt = fmaxf(mt, sv[jt][r]);
        }
        mt = fmaxf(mt, __shfl_xor(mt, 16, 64));
        mt = fmaxf(mt, __shfl_xor(mt, 32, 64));
        float psum = 0.f;
        #pragma unroll
        for (int jt = 0; jt < 4; ++jt) {
            float p0 = __expf(sv[jt][0] - mt);
            float p1 = __expf(sv[jt][1] - mt);
            float p2 = __expf(sv[jt][2] - mt);
            float p3 = __expf(sv[jt][3] - mt);
            psum += (p0 + p1) + (p2 + p3);
            uint2 wv;
            wv.x = (unsigned)bf16_bits(p0) | ((unsigned)bf16_bits(p1) << 16);
            wv.y = (unsigned)bf16_bits(p2) | ((unsigned)bf16_bits(p3) << 16);
            *(uint2*)&P_lds[lr][jt * 16 + lk * 4] = wv;
        }
        psum += __shfl_xor(psum, 16, 64);
        psum += __shfl_xor(psum, 32, 64);
        __syncthreads();

        f32x4 oacc[2];
        oacc[0] = (f32x4){0.f, 0.f, 0.f, 0.f};
        oacc[1] = (f32x4){0.f, 0.f, 0.f, 0.f};
        #pragma unroll
        for (int kst = 0; kst < 2; ++kst) {
            short8 bfv = *(const short8*)&P_lds[lr][kst * 32 + lk * 8];
            #pragma unroll
            for (int dt = 0; dt < 2; ++dt) {
                short8 af = *(const short8*)&VT_lds[dt * 16 + lr][kst * 32 + lk * 8];
                oacc[dt] = __builtin_amdgcn_mfma_f32_16x16x32_bf16(af, bfv, oacc[dt], 0, 0, 0);
            }
        }
        if (i < NWIN_N) {
            float inv = 1.f / psum;
            unsigned short* orow = (unsigned short*)outp + (rowbase + i) * CH + head * HD;
            #pragma unroll
            for (int dt = 0; dt < 2; ++dt) {
                uint2 wv;
                wv.x = (unsigned)bf16_bits(oacc[dt][0] * inv)
                     | ((unsigned)bf16_bits(oacc[dt][1] * inv) << 16);
                wv.y = (unsigned)bf16_bits(oacc[dt][2] * inv)
                     | ((unsigned)bf16_bits(oacc[dt][3] * inv) << 16);
                *(uint2*)&orow[dt * 16 + lk * 4] = wv;
            }
        }
        __syncthreads();
    }
}

// ---------------------------------------------------------------------------
// 5) cross-channel attention, MFMA flash. qkvc pitch 168: q@0, k@56, v@112.
// ---------------------------------------------------------------------------
__global__ __launch_bounds__(256) void cross_attn_mfma_kernel(
    const __hip_bfloat16* __restrict__ qkv,   // [262144][168]
    __hip_bfloat16* __restrict__ outp)        // [262144][64] padded
{
    __shared__ __align__(16) unsigned short K_lds[64][72];
    __shared__ __align__(16) unsigned short VT_lds[64][72];
    __shared__ __align__(16) unsigned short P_lds[2][64][72]; // [0] doubles as V-scratch

    const int bc = blockIdx.x;
    const size_t base = (size_t)bc * 256;
    const int tid  = threadIdx.x;
    const int lane = tid & 63;
    const int wave = tid >> 6;
    const int i0w  = wave * 64;
    const int lr   = lane & 15;
    const int lk   = lane >> 4;
    const int prow = wave * 16 + lr;

    const unsigned short* q16 = (const unsigned short*)qkv;
    const float inv7 = 1.f / 7.f;   // 49^-0.5
    const short8 zf = (short8){0, 0, 0, 0, 0, 0, 0, 0};

    short8 qf[4][2];
    #pragma unroll
    for (int it = 0; it < 4; ++it) {
        const unsigned short* qrow = q16 + (base + i0w + it * 16 + lr) * 168;
        #pragma unroll
        for (int kst = 0; kst < 2; ++kst) {
            int k0 = lk * 8 + kst * 32;
            qf[it][kst] = (k0 <= 48) ? *(const short8*)(qrow + k0) : zf;
        }
    }

    float m_run[4], l_run[4];
    f32x4 acc_o[4][4];   // [dt][it]
    #pragma unroll
    for (int it = 0; it < 4; ++it) { m_run[it] = -1e30f; l_run[it] = 0.f; }
    #pragma unroll
    for (int dt = 0; dt < 4; ++dt)
        #pragma unroll
        for (int it = 0; it < 4; ++it) acc_o[dt][it] = (f32x4){0.f, 0.f, 0.f, 0.f};

    for (int jt4 = 0; jt4 < 4; ++jt4) {
        const int j0 = jt4 * 64;
        {
            const int jr = tid >> 3, c8 = (tid & 7) * 8;
            #pragma unroll
            for (int h = 0; h < 2; ++h) {
                int jj = jr + h * 32;
                const unsigned short* row = q16 + (base + j0 + jj) * 168;
                *(short8*)&K_lds[jj][c8]    = (c8 <= 48) ? *(const short8*)(row + 56 + c8) : zf;
                *(short8*)&P_lds[0][jj][c8] = (c8 <= 48) ? *(const short8*)(row + 112 + c8) : zf;
            }
        }
        __syncthreads();
        {
            const int jj = tid & 63, dg = tid >> 6;
            #pragma unroll
            for (int e = 0; e < 16; ++e) {
                int d = dg * 16 + e;
                VT_lds[d][jj] = P_lds[0][jj][d];
            }
        }
        __syncthreads();

        #pragma unroll
        for (int it = 0; it < 4; ++it) {
            unsigned short* prowp = &P_lds[it & 1][prow][0];
            f32x4 sacc[4];
            #pragma unroll
            for (int jt = 0; jt < 4; ++jt) sacc[jt] = (f32x4){0.f, 0.f, 0.f, 0.f};
            #pragma unroll
            for (int kst = 0; kst < 2; ++kst) {
                #pragma unroll
                for (int jt = 0; jt < 4; ++jt) {
                    short8 af = *(const short8*)&K_lds[jt * 16 + lr][lk * 8 + kst * 32];
                    sacc[jt] = __builtin_amdgcn_mfma_f32_16x16x32_bf16(
                        af, qf[it][kst], sacc[jt], 0, 0, 0);
                }
            }
            float mt = -1e30f;
            #pragma unroll
            for (int jt = 0; jt < 4; ++jt)
                #pragma unroll
                for (int r = 0; r < 4; ++r) mt = fmaxf(mt, sacc[jt][r]);
            mt = fmaxf(mt, __shfl_xor(mt, 16, 64));
            mt = fmaxf(mt, __shfl_xor(mt, 32, 64));
            float mnew = fmaxf(m_run[it], mt * inv7);
            float corr = __expf(m_run[it] - mnew);
            m_run[it] = mnew;
            l_run[it] *= corr;
            #pragma unroll
            for (int dt = 0; dt < 4; ++dt)
                #pragma unroll
                for (int r = 0; r < 4; ++r) acc_o[dt][it][r] *= corr;

            float psum = 0.f;
            #pragma unroll
            for (int jt = 0; jt < 4; ++jt) {
                float p0 = __expf(sacc[jt][0] * inv7 - mnew);
                float p1 = __expf(sacc[jt][1] * inv7 - mnew);
                float p2 = __expf(sacc[jt][2] * inv7 - mnew);
                float p3 = __expf(sacc[jt][3] * inv7 - mnew);
                psum += (p0 + p1) + (p2 + p3);
                uint2 wv;
                wv.x = (unsigned)bf16_bits(p0) | ((unsigned)bf16_bits(p1) << 16);
                wv.y = (unsigned)bf16_bits(p2) | ((unsigned)bf16_bits(p3) << 16);
                *(uint2*)(prowp + jt * 16 + lk * 4) = wv;
            }
            psum += __shfl_xor(psum, 16, 64);
            psum += __shfl_xor(psum, 32, 64);
            l_run[it] += psum;

            #pragma unroll
            for (int kst = 0; kst < 2; ++kst) {
                short8 bfv = *(const short8*)(prowp + kst * 32 + lk * 8);
                #pragma unroll
                for (int dt = 0; dt < 4; ++dt) {
                    short8 af = *(const short8*)&VT_lds[dt * 16 + lr][kst * 32 + lk * 8];
                    acc_o[dt][it] = __builtin_amdgcn_mfma_f32_16x16x32_bf16(
                        af, bfv, acc_o[dt][it], 0, 0, 0);
                }
            }
        }
        __syncthreads();
    }

    #pragma unroll
    for (int it = 0; it < 4; ++it) {
        float inv = 1.f / l_run[it];
        unsigned short* orow = (unsigned short*)outp + (base + i0w + it * 16 + lr) * 64;
        #pragma unroll
        for (int dt = 0; dt < 4; ++dt) {
            uint2 wv;
            wv.x = (unsigned)bf16_bits(acc_o[dt][it][0] * inv)
                 | ((unsigned)bf16_bits(acc_o[dt][it][1] * inv) << 16);
            wv.y = (unsigned)bf16_bits(acc_o[dt][it][2] * inv)
                 | ((unsigned)bf16_bits(acc_o[dt][it][3] * inv) << 16);
            *(uint2*)&orow[dt * 16 + lk * 4] = wv;
        }
    }
}

// ---------------------------------------------------------------------------
// 6a) FUSED transpose + pad: patches -> pc_pad[((b*256+c)*256+p)*64+t]
// ---------------------------------------------------------------------------
__global__ __launch_bounds__(256) void transpose_pad_kernel(
    const __hip_bfloat16* __restrict__ patches, unsigned short* __restrict__ pc_pad)
{
    __shared__ __hip_bfloat16 T[64][66];
    int b = blockIdx.z;
    int r0 = blockIdx.y * 64, c0 = blockIdx.x * 64;
    const __hip_bfloat16* s = patches + (size_t)b * 12544 * 256;
    int tid = threadIdx.x;
    int lr4 = tid >> 6, lc = tid & 63;

    #pragma unroll
    for (int l = 0; l < 16; ++l) {
        int rr = l * 4 + lr4;
        T[rr][lc] = s[(size_t)(r0 + rr) * 256 + c0 + lc];
    }
    __syncthreads();
    int r = r0 + lc;
    int p = r / 49, t = r - p * 49;
    #pragma unroll
    for (int l = 0; l < 16; ++l) {
        int cc = l * 4 + lr4;
        size_t dst = (((size_t)(b * 256 + c0 + cc) * 256) + p) * 64 + t;
        pc_pad[dst] = *(unsigned short*)&T[lc][cc];
    }
    int plo = r0 / 49, phi = (r0 + 63) / 49;
    for (int pp = plo; pp <= phi; ++pp) {
        if (pp >= 256) break;
        for (int idx = tid; idx < 64 * 15; idx += 256) {
            int cc = idx / 15, t2 = 49 + idx % 15;
            size_t dst = (((size_t)(b * 256 + c0 + cc) * 256) + pp) * 64 + t2;
            pc_pad[dst] = 0;
        }
    }
}

// ---------------------------------------------------------------------------
// 6) batched 2D transpose: src[b][R][Cc] -> dst[b][Cc][R]; grid (Cc/64,R/64,B)
// ---------------------------------------------------------------------------
__global__ __launch_bounds__(256) void transpose_bf16_kernel(
    const __hip_bfloat16* __restrict__ src, __hip_bfloat16* __restrict__ dst,
    int R, int Cc)
{
    __shared__ __hip_bfloat16 T[64][66];
    int b = blockIdx.z;
    int r0 = blockIdx.y * 64, c0 = blockIdx.x * 64;
    const __hip_bfloat16* s = src + (size_t)b * R * Cc;
    __hip_bfloat16* d = dst + (size_t)b * R * Cc;
    int tid = threadIdx.x;
    int lr = tid >> 6, lc = tid & 63;

    #pragma unroll
    for (int l = 0; l < 16; ++l) {
        int rr = l * 4 + lr;
        T[rr][lc] = s[(size_t)(r0 + rr) * Cc + c0 + lc];
    }
    __syncthreads();
    #pragma unroll
    for (int l = 0; l < 16; ++l) {
        int cc = l * 4 + lr;
        d[(size_t)(c0 + cc) * R + r0 + lc] = T[lc][cc];
    }
}

// ---------------------------------------------------------------------------
__global__ void ws_marker_kernel(float* __restrict__ out0)
{
    if (threadIdx.x == 0) out0[0] = 777.0f;
}

// ---------------------------------------------------------------------------
extern "C" void kernel_launch(void* const* d_in, const int* in_sizes, int n_in,
                              void* d_out, int out_size, void* d_ws, size_t ws_size,
                              hipStream_t stream)
{
    const float* x        = (const float*)d_in[0];
    const float* gamma    = (const float*)d_in[1];
    const float* beta     = (const float*)d_in[2];
    const float* qkv_l_w  = (const float*)d_in[3];
    const float* qkv_l_b  = (const float*)d_in[4];
    const float* proj_l_w = (const float*)d_in[5];
    const float* proj_l_b = (const float*)d_in[6];
    const float* rpb      = (const float*)d_in[7];
    const float* qkv_c_w  = (const float*)d_in[8];
    const float* qkv_c_b  = (const float*)d_in[9];
    const float* proj_c_w = (const float*)d_in[10];
    const float* proj_c_b = (const float*)d_in[11];
    const float* proj_w   = (const float*)d_in[12];

    float* out0 = (float*)d_out;
    float* out1 = out0 + ELEMS;

    copy_f32_kernel<<<(int)(ELEMS / 1024), 256, 0, stream>>>(x, out1);

    char* ws = (char*)d_ws;
    if (ws_size < 6 * SZ) {
        ws_marker_kernel<<<1, 64, 0, stream>>>(out0);
        return;
    }

    const size_t P = SZ;
    // plane/lifetime map (identical to R13, verified):
    __hip_bfloat16* localOut  = (__hip_bfloat16*)(ws + 0 * P);
    unsigned short* wt_qkv_l  = (unsigned short*)(ws + 0 * P);
    float*          biasb     = (float*)(ws + 0 * P + 0x80000);
    __hip_bfloat16* patches   = (__hip_bfloat16*)(ws + 1 * P);
    __hip_bfloat16* qkv_l     = (__hip_bfloat16*)(ws + 2 * P);
    __hip_bfloat16* attnL     = (__hip_bfloat16*)(ws + 5 * P);
    char*           G         = ws + 4 * P + 0xB00000;
    unsigned short* wt_proj_l = (unsigned short*)(G + 0x000000);
    unsigned short* wt_qkv_c  = (unsigned short*)(G + 0x080000);
    unsigned short* wt_proj_c = (unsigned short*)(G + 0x100000);
    unsigned short* wt_final  = (unsigned short*)(G + 0x180000);
    float*          biasc     = (float*)(G + 0x300000);
    __hip_bfloat16* pc_pad    = (__hip_bfloat16*)(ws + 6 * P - (size_t)262144 * 64 * 2);
    __hip_bfloat16* qkvc      = (__hip_bfloat16*)(ws + 1 * P);
    __hip_bfloat16* crossAttn = pc_pad;
    __hip_bfloat16* crossProj = (__hip_bfloat16*)(ws + 1 * P);
    __hip_bfloat16* crossT    = (__hip_bfloat16*)(ws + 2 * P);

    // K0) combined prep A: wt_qkv_l + biasb (needed before K3/K4)
    prep_a_kernel<<<896, 256, 0, stream>>>(qkv_l_w, wt_qkv_l, rpb, biasb);
    // K1) LN + window partition
    ln_partition_kernel<<<BB * HH * 7, 256, 0, stream>>>(x, gamma, beta, patches);
    // K3) qkv_local: [50176,256] @ [256,768], pitch 768
    gemm_mfma_kernel<<<dim3(12, 392), 256, 0, stream>>>(
        patches, nullptr, 256, wt_qkv_l, qkv_l_b, qkv_l, nullptr, 50176, 768, 256, 768);
    // K4) local attention (MFMA)
    local_attn_mfma_kernel<<<1024 * NHEAD, 64, 0, stream>>>(qkv_l, biasb, attnL);
    // K4.5) combined prep B (G region free after K4)
    prep_b_kernel<<<833, 256, 0, stream>>>(
        proj_l_w, wt_proj_l, qkv_c_w, wt_qkv_c, qkv_c_b, biasc,
        proj_c_w, wt_proj_c, proj_w, wt_final);
    // K5) proj_local: [50176,256] @ [256,256], pitch 256
    gemm_mfma_kernel<<<dim3(4, 392), 256, 0, stream>>>(
        attnL, nullptr, 256, wt_proj_l, proj_l_b, localOut, nullptr, 50176, 256, 256, 256);
    // K6) fused transpose+pad: patches -> pc_pad [262144][64]
    transpose_pad_kernel<<<dim3(4, 196, BB), 256, 0, stream>>>(
        patches, (unsigned short*)pc_pad);
    // K7) qkv_cross: [262144,64pad] @ [64,161 remapped] -> qkvc pitch 168
    gemm_mfma_kernel<<<dim3(3, 2048), 256, 0, stream>>>(
        pc_pad, nullptr, 64, wt_qkv_c, biasc, qkvc, nullptr, 262144, 161, 64, 168);
    // K8) cross attention (reads pitch 168, aligned segments)
    cross_attn_mfma_kernel<<<1024, 256, 0, stream>>>(qkvc, crossAttn);
    // K9) proj_cross: [262144,64pad] @ [64,49] -> dense [262144][49]
    gemm_mfma_kernel<<<dim3(1, 2048), 256, 0, stream>>>(
        crossAttn, nullptr, 64, wt_proj_c, proj_c_b, crossProj, nullptr, 262144, 49, 64, 49);
    // K10) crossT = per-b transpose back
    transpose_bf16_kernel<<<dim3(196, 4, BB), 256, 0, stream>>>(crossProj, crossT, 256, 12544);
    // K11) final: concat[localOut|crossT] @ proj_w -> out0 fp32 BCHW
    gemm_mfma_kernel<<<dim3(4, 392), 256, 0, stream>>>(
        localOut, crossT, 256, wt_final, nullptr, nullptr, out0, 50176, 256, 512, 256);
}

// Round 20
// 303.760 us; speedup vs baseline: 1.3410x; 1.0942x over previous
//
#include <hip/hip_runtime.h>
#include <hip/hip_bf16.h>

// Problem geometry (fixed by the reference):
// B=4, C=256, H=W=112, ps=7, N=49, nP=256 windows/batch, NH=8, d=32.
// Inputs fp32. d_out is FP32: [out | shortcut], each (B,C,H,W).

#define PS 7
#define NWIN_N 49
#define CH 256
#define HH 112
#define WW 112
#define BB 4
#define NHEAD 8
#define HD 32

static constexpr size_t ELEMS = (size_t)BB * CH * HH * WW;      // 12,845,056
static constexpr size_t SZ    = ELEMS * 2;                      // 25,690,112 B (one bf16 plane)

typedef __attribute__((ext_vector_type(8))) short short8;
typedef __attribute__((ext_vector_type(4))) float f32x4;

static __device__ __forceinline__ unsigned short bf16_bits(float v) {
    __hip_bfloat16 h = __float2bfloat16(v);
    return *reinterpret_cast<unsigned short*>(&h);
}

// async global->LDS, 16B per lane; lptr wave-uniform, gptr per-lane.
static __device__ __forceinline__ void gload_lds16(const void* g, void* l) {
    __builtin_amdgcn_global_load_lds(
        (const __attribute__((address_space(1))) unsigned int*)g,
        (__attribute__((address_space(3))) unsigned int*)l, 16, 0, 0);
}

// ---------------------------------------------------------------------------
// 1) LayerNorm over C + window partition -> patches[(b*256+p)*49+i][c] (bf16)
// ---------------------------------------------------------------------------
__global__ __launch_bounds__(256) void ln_partition_kernel(
    const float* __restrict__ x, const float* __restrict__ gamma,
    const float* __restrict__ beta, __hip_bfloat16* __restrict__ patches)
{
    int blk = blockIdx.x;
    int seg = blk % 7;
    int bh = blk / 7;
    int h = bh % HH, b = bh / HH;
    int w0 = seg * 16;
    int tid = threadIdx.x;

    __shared__ float X[256][17];
    __shared__ float mus[16], rstds[16];

    #pragma unroll
    for (int l = 0; l < 16; ++l) {
        int idx = l * 256 + tid;
        int c = idx >> 4, wl = idx & 15;
        X[c][wl] = x[((size_t)(b * CH + c) * HH + h) * WW + w0 + wl];
    }
    __syncthreads();

    if (tid < 16) {
        float s = 0.f, ss = 0.f;
        for (int c = 0; c < 256; ++c) { float v = X[c][tid]; s += v; ss += v * v; }
        float mu = s * (1.f / 256.f);
        float var = ss * (1.f / 256.f) - mu * mu;
        mus[tid] = mu;
        rstds[tid] = rsqrtf(var + 1e-5f);
    }
    __syncthreads();

    int c = tid;
    float g = gamma[c], be = beta[c];
    int hp = h / PS, r = h - hp * PS;
    #pragma unroll
    for (int wl = 0; wl < 16; ++wl) {
        int w = w0 + wl;
        int wp = w / PS, cc = w - wp * PS;
        int win = (b * 16 + hp) * 16 + wp;
        int i = r * PS + cc;
        float v = (X[c][wl] - mus[wl]) * rstds[wl] * g + be;
        patches[((size_t)win * NWIN_N + i) * CH + c] = __float2bfloat16(v);
    }
}

// ---------------------------------------------------------------------------
// 2) shortcut: fp32 -> fp32 copy (float4)
// ---------------------------------------------------------------------------
__global__ __launch_bounds__(256) void copy_f32_kernel(
    const float* __restrict__ x, float* __restrict__ out)
{
    size_t i = ((size_t)blockIdx.x * 256 + threadIdx.x) * 4;
    *(float4*)(out + i) = *(const float4*)(x + i);
}

// ---------------------------------------------------------------------------
// Combined prep A (launched before K3): wt_qkv_l (768 blocks) + biasb (128).
// ---------------------------------------------------------------------------
__global__ __launch_bounds__(256) void prep_a_kernel(
    const float* __restrict__ qkv_l_w, unsigned short* __restrict__ wt_qkv_l,
    const float* __restrict__ rpb, float* __restrict__ biasb)
{
    int b = blockIdx.x;
    if (b < 768) {
        int idx = b * 256 + threadIdx.x;          // Kpad=256, Npad=768, full
        int n = idx >> 8, k = idx & 255;
        wt_qkv_l[idx] = bf16_bits(qkv_l_w[(size_t)k * 768 + n]);
    } else {
        int idx = (b - 768) * 256 + threadIdx.x;  // < 32768
        int head = idx >> 12;
        int rem = idx & 4095;
        int i = rem >> 6, j = rem & 63;
        float v;
        if (j >= NWIN_N) v = -1e9f;
        else if (i >= NWIN_N) v = 0.f;
        else {
            int ri = i / 7, ci = i - ri * 7;
            int rj = j / 7, cj = j - rj * 7;
            v = rpb[((ri - rj + 6) * 13 + (ci - cj + 6)) * NHEAD + head];
        }
        biasb[idx] = v;
    }
}

// ---------------------------------------------------------------------------
// Combined prep B (launched after K4, G region free): wt_proj_l [0,256) +
// wt_qkv_c remap [256,304) + biasc {304} + wt_proj_c [305,321) +
// wt_final [321,833).
// ---------------------------------------------------------------------------
__global__ __launch_bounds__(256) void prep_b_kernel(
    const float* __restrict__ proj_l_w, unsigned short* __restrict__ wt_proj_l,
    const float* __restrict__ qkv_c_w, unsigned short* __restrict__ wt_qkv_c,
    const float* __restrict__ qkv_c_b, float* __restrict__ biasc,
    const float* __restrict__ proj_c_w, unsigned short* __restrict__ wt_proj_c,
    const float* __restrict__ proj_w, unsigned short* __restrict__ wt_final)
{
    int b = blockIdx.x;
    int t = threadIdx.x;
    if (b < 256) {
        int idx = b * 256 + t;                    // Kpad=256, Npad=256, full
        int n = idx >> 8, k = idx & 255;
        wt_proj_l[idx] = bf16_bits(proj_l_w[(size_t)k * 256 + n]);
    } else if (b < 304) {
        int idx = (b - 256) * 256 + t;            // < 12288 = 192*64
        int n = idx >> 6, k = idx & 63;
        int s = -1;
        if (n < 49) s = n;
        else if (n >= 56 && n < 105) s = n - 7;
        else if (n >= 112 && n < 161) s = n - 14;
        float v = (s >= 0 && k < 49) ? qkv_c_w[(size_t)k * 147 + s] : 0.f;
        wt_qkv_c[idx] = bf16_bits(v);
    } else if (b == 304) {
        if (t < 192) {
            int n = t, s = -1;
            if (n < 49) s = n;
            else if (n >= 56 && n < 105) s = n - 7;
            else if (n >= 112 && n < 161) s = n - 14;
            biasc[n] = (s >= 0) ? qkv_c_b[s] : 0.f;
        }
    } else if (b < 321) {
        int idx = (b - 305) * 256 + t;            // < 4096 = 64*64
        int n = idx >> 6, k = idx & 63;
        float v = (n < 49 && k < 49) ? proj_c_w[(size_t)k * 49 + n] : 0.f;
        wt_proj_c[idx] = bf16_bits(v);
    } else {
        int idx = (b - 321) * 256 + t;            // < 131072; Kpad=512, Npad=256
        int n = idx >> 9, k = idx & 511;
        wt_final[idx] = bf16_bits(proj_w[(size_t)k * 256 + n]);
    }
}

// ---------------------------------------------------------------------------
// Unified MFMA GEMM (R13/R19 proven form): BM=128, BN=64, BK=64; 256 thr =
// 4 waves (2x2); 16x16x32 MFMA. gload_lds(16B) staging, linear LDS dest +
// pre-swizzled global source + XOR reads (rule #21). XCD-chunked tile
// swizzle (all call sites have ntiles % 8 == 0).
// R20: Cf (fp32 BCHW) epilogue now stages through LDS and stores with lanes
// along m (w-contiguous runs of 7) -> ~7x better write-line utilization.
// Alds/Wlds unioned into one 24 KB buffer so the fp32 stage fits (16.9 KB).
// ---------------------------------------------------------------------------
__global__ __launch_bounds__(256) void gemm_mfma_kernel(
    const __hip_bfloat16* __restrict__ A1p, const __hip_bfloat16* __restrict__ A2p,
    int K1, const unsigned short* __restrict__ Wt, const float* __restrict__ bias,
    __hip_bfloat16* __restrict__ Cb, float* __restrict__ Cf,
    int M, int N, int K, int pitchN)
{
    __shared__ __align__(16) unsigned short S[128 * 64 + 64 * 64];   // 24 KB
    unsigned short* Alds = S;              // [128 rows][8 slots of 8]
    unsigned short* Wlds = S + 128 * 64;   // [64 rows][8 slots of 8]
    const unsigned short* A1 = (const unsigned short*)A1p;
    const unsigned short* A2 = (const unsigned short*)A2p;

    const int nb = gridDim.x;
    const int ntiles = nb * gridDim.y;
    const int bid = blockIdx.y * nb + blockIdx.x;
    const int chunk = ntiles >> 3;
    const int tile = (bid & 7) * chunk + (bid >> 3);
    const int m0 = (tile / nb) * 128, n0 = (tile % nb) * 64;

    const int tid = threadIdx.x, lane = tid & 63, wave = tid >> 6;
    const int wm = wave >> 1, wn = wave & 1;
    const int lr = lane & 15, lk = lane >> 4;

    f32x4 acc[4][2];
    #pragma unroll
    for (int i = 0; i < 4; ++i)
        #pragma unroll
        for (int j = 0; j < 2; ++j) acc[i][j] = (f32x4){0.f, 0.f, 0.f, 0.f};

    for (int k0 = 0; k0 < K; k0 += 64) {
        #pragma unroll
        for (int i = 0; i < 4; ++i) {
            int s_lin = i * 256 + tid;
            int row = s_lin >> 3, sl = s_lin & 7;
            int c8 = ((sl ^ (row & 7)) << 3);
            int k = k0 + c8;
            const unsigned short* src = (k < K1)
                ? A1 + (size_t)(m0 + row) * K1 + k
                : A2 + (size_t)(m0 + row) * (K - K1) + (k - K1);
            gload_lds16(src, Alds + (size_t)(i * 256 + wave * 64) * 8);
        }
        #pragma unroll
        for (int i = 0; i < 2; ++i) {
            int s_lin = i * 256 + tid;
            int row = s_lin >> 3, sl = s_lin & 7;
            int c8 = ((sl ^ (row & 7)) << 3);
            gload_lds16(Wt + (size_t)(n0 + row) * K + k0 + c8,
                        Wlds + (size_t)(i * 256 + wave * 64) * 8);
        }
        __syncthreads();
        #pragma unroll
        for (int kk = 0; kk < 64; kk += 32) {
            short8 a[4], w[2];
            #pragma unroll
            for (int mi = 0; mi < 4; ++mi) {
                int r = wm * 64 + mi * 16 + lr;
                int sl = (kk >> 3) + lk;
                a[mi] = *(const short8*)&Alds[(r << 6) + (((sl) ^ (r & 7)) << 3)];
            }
            #pragma unroll
            for (int nj = 0; nj < 2; ++nj) {
                int r = wn * 32 + nj * 16 + lr;
                int sl = (kk >> 3) + lk;
                w[nj] = *(const short8*)&Wlds[(r << 6) + (((sl) ^ (r & 7)) << 3)];
            }
            #pragma unroll
            for (int mi = 0; mi < 4; ++mi)
                #pragma unroll
                for (int nj = 0; nj < 2; ++nj)
                    acc[mi][nj] = __builtin_amdgcn_mfma_f32_16x16x32_bf16(
                        a[mi], w[nj], acc[mi][nj], 0, 0, 0);
        }
        __syncthreads();
    }

    if (Cb) {
        if ((pitchN & 7) == 0) {
            #pragma unroll
            for (int nj = 0; nj < 2; ++nj) {
                int n = n0 + wn * 32 + nj * 16 + lr;
                float bv = (bias && n < N) ? bias[n] : 0.f;
                int col = wn * 32 + nj * 16 + lr;
                #pragma unroll
                for (int mi = 0; mi < 4; ++mi)
                    #pragma unroll
                    for (int r = 0; r < 4; ++r) {
                        int row = wm * 64 + mi * 16 + lk * 4 + r;
                        int idx = (row << 6) + (((col >> 3) ^ (row & 7)) << 3) + (col & 7);
                        Alds[idx] = bf16_bits(acc[mi][nj][r] + bv);
                    }
            }
            __syncthreads();
            #pragma unroll
            for (int i = 0; i < 4; ++i) {
                int s = tid + 256 * i;
                int row = s >> 3, sl = s & 7;
                if (n0 + sl * 8 + 8 <= pitchN)
                    *(short8*)((unsigned short*)Cb + (size_t)(m0 + row) * pitchN + n0 + sl * 8) =
                        *(const short8*)&Alds[(row << 6) + (((sl) ^ (row & 7)) << 3)];
            }
        } else {
            #pragma unroll
            for (int nj = 0; nj < 2; ++nj) {
                int n = n0 + wn * 32 + nj * 16 + lr;
                if (n >= N) continue;
                float bv = bias ? bias[n] : 0.f;
                #pragma unroll
                for (int mi = 0; mi < 4; ++mi) {
                    #pragma unroll
                    for (int r = 0; r < 4; ++r) {
                        int m = m0 + wm * 64 + mi * 16 + lk * 4 + r;
                        ((unsigned short*)Cb)[(size_t)m * pitchN + n] =
                            bf16_bits(acc[mi][nj][r] + bv);
                    }
                }
            }
        }
    } else {
        // fp32 BCHW epilogue, LDS-staged: lanes run along m -> w-contiguous
        // runs of 7 per (ch,h). Two m-halves of 64 through Sf[64][66].
        float* Sf = (float*)S;    // 64*66*4 = 16.9 KB <= 24 KB
        #pragma unroll
        for (int half = 0; half < 2; ++half) {
            if (wm == half) {
                #pragma unroll
                for (int nj = 0; nj < 2; ++nj) {
                    int col = wn * 32 + nj * 16 + lr;
                    #pragma unroll
                    for (int mi = 0; mi < 4; ++mi)
                        #pragma unroll
                        for (int r = 0; r < 4; ++r)
                            Sf[(mi * 16 + lk * 4 + r) * 66 + col] = acc[mi][nj][r];
                }
            }
            __syncthreads();
            {
                int mlo = lane;                    // 0..63, consecutive m
                int m = m0 + half * 64 + mlo;
                int b = m / 12544, rem = m - b * 12544;
                int p = rem / 49, t = rem - p * 49;
                int hh = (p >> 4) * 7 + t / 7, ww2 = (p & 15) * 7 + (t % 7);
                size_t ob = ((size_t)(b * 256 + n0) * HH + hh) * WW + ww2;
                #pragma unroll
                for (int c = 0; c < 16; ++c) {
                    int col = wave * 16 + c;
                    Cf[ob + (size_t)col * (HH * WW)] = Sf[mlo * 66 + col];
                }
            }
            __syncthreads();
        }
    }
}

// ---------------------------------------------------------------------------
// 4) local windowed attention, MFMA. One wave per (win, head).
// ---------------------------------------------------------------------------
__global__ __launch_bounds__(64) void local_attn_mfma_kernel(
    const __hip_bfloat16* __restrict__ qkv,   // [50176][768] q|k|v
    const float* __restrict__ biasb,          // [8][64][64] fp32 padded
    __hip_bfloat16* __restrict__ outp)        // [50176][256]
{
    __shared__ __align__(16) unsigned short VT_lds[32][72];
    __shared__ __align__(16) unsigned short P_lds[16][72];

    const int win  = blockIdx.x >> 3;
    const int head = blockIdx.x & 7;
    const int lane = threadIdx.x;
    const int lr = lane & 15, lk = lane >> 4;
    const unsigned short* q16 = (const unsigned short*)qkv;
    const size_t rowbase = (size_t)win * NWIN_N;
    const float scale = 0.17677669529663687f;   // 32^-0.5

    for (int t = 0; t < 32; ++t) {
        int idx = lane + 64 * t;
        int j = idx >> 5, d = idx & 31;
        unsigned short v = 0;
        if (j < NWIN_N) v = q16[(rowbase + j) * 768 + 512 + head * HD + d];
        VT_lds[d][j] = v;
    }

    short8 kf[4], qf[4];
    #pragma unroll
    for (int jt = 0; jt < 4; ++jt) {
        int j = jt * 16 + lr;
        short8 f = *(const short8*)(q16 + (rowbase + j) * 768 + 256 + head * HD + lk * 8);
        if (j >= NWIN_N) {
            #pragma unroll
            for (int e = 0; e < 8; ++e) f[e] = 0;
        }
        kf[jt] = f;
    }
    #pragma unroll
    for (int it = 0; it < 4; ++it) {
        int i = it * 16 + lr;
        qf[it] = *(const short8*)(q16 + (rowbase + i) * 768 + head * HD + lk * 8);
    }
    __syncthreads();

    #pragma unroll
    for (int it = 0; it < 4; ++it) {
        const int i = it * 16 + lr;
        f32x4 sacc[4];
        #pragma unroll
        for (int jt = 0; jt < 4; ++jt) {
            f32x4 z = (f32x4){0.f, 0.f, 0.f, 0.f};
            sacc[jt] = __builtin_amdgcn_mfma_f32_16x16x32_bf16(kf[jt], qf[it], z, 0, 0, 0);
        }
        const float* brow = biasb + head * 4096 + i * 64;
        float sv[4][4];
        float mt = -1e30f;
        #pragma unroll
        for (int jt = 0; jt < 4; ++jt) {
            float4 bv = *(const float4*)&brow[jt * 16 + lk * 4];
            sv[jt][0] = sacc[jt][0] * scale + bv.x;
            sv[jt][1] = sacc[jt][1] * scale + bv.y;
            sv[jt][2] = sacc[jt][2] * scale + bv.z;
            sv[jt][3] = sacc[jt][3] * scale + bv.w;
            #pragma unroll
            for (int r = 0; r < 4; ++r) mt = fmaxf(mt, sv[jt][r]);
        }
        mt = fmaxf(mt, __shfl_xor(mt, 16, 64));
        mt = fmaxf(mt, __shfl_xor(mt, 32, 64));
        float psum = 0.f;
        #pragma unroll
        for (int jt = 0; jt < 4; ++jt) {
            float p0 = __expf(sv[jt][0] - mt);
            float p1 = __expf(sv[jt][1] - mt);
            float p2 = __expf(sv[jt][2] - mt);
            float p3 = __expf(sv[jt][3] - mt);
            psum += (p0 + p1) + (p2 + p3);
            uint2 wv;
            wv.x = (unsigned)bf16_bits(p0) | ((unsigned)bf16_bits(p1) << 16);
            wv.y = (unsigned)bf16_bits(p2) | ((unsigned)bf16_bits(p3) << 16);
            *(uint2*)&P_lds[lr][jt * 16 + lk * 4] = wv;
        }
        psum += __shfl_xor(psum, 16, 64);
        psum += __shfl_xor(psum, 32, 64);
        __syncthreads();

        f32x4 oacc[2];
        oacc[0] = (f32x4){0.f, 0.f, 0.f, 0.f};
        oacc[1] = (f32x4){0.f, 0.f, 0.f, 0.f};
        #pragma unroll
        for (int kst = 0; kst < 2; ++kst) {
            short8 bfv = *(const short8*)&P_lds[lr][kst * 32 + lk * 8];
            #pragma unroll
            for (int dt = 0; dt < 2; ++dt) {
                short8 af = *(const short8*)&VT_lds[dt * 16 + lr][kst * 32 + lk * 8];
                oacc[dt] = __builtin_amdgcn_mfma_f32_16x16x32_bf16(af, bfv, oacc[dt], 0, 0, 0);
            }
        }
        if (i < NWIN_N) {
            float inv = 1.f / psum;
            unsigned short* orow = (unsigned short*)outp + (rowbase + i) * CH + head * HD;
            #pragma unroll
            for (int dt = 0; dt < 2; ++dt) {
                uint2 wv;
                wv.x = (unsigned)bf16_bits(oacc[dt][0] * inv)
                     | ((unsigned)bf16_bits(oacc[dt][1] * inv) << 16);
                wv.y = (unsigned)bf16_bits(oacc[dt][2] * inv)
                     | ((unsigned)bf16_bits(oacc[dt][3] * inv) << 16);
                *(uint2*)&orow[dt * 16 + lk * 4] = wv;
            }
        }
        __syncthreads();
    }
}

// ---------------------------------------------------------------------------
// 5) cross-channel attention, MFMA flash. qkvc pitch 168: q@0, k@56, v@112.
// ---------------------------------------------------------------------------
__global__ __launch_bounds__(256) void cross_attn_mfma_kernel(
    const __hip_bfloat16* __restrict__ qkv,   // [262144][168]
    __hip_bfloat16* __restrict__ outp)        // [262144][64] padded
{
    __shared__ __align__(16) unsigned short K_lds[64][72];
    __shared__ __align__(16) unsigned short VT_lds[64][72];
    __shared__ __align__(16) unsigned short P_lds[2][64][72]; // [0] doubles as V-scratch

    const int bc = blockIdx.x;
    const size_t base = (size_t)bc * 256;
    const int tid  = threadIdx.x;
    const int lane = tid & 63;
    const int wave = tid >> 6;
    const int i0w  = wave * 64;
    const int lr   = lane & 15;
    const int lk   = lane >> 4;
    const int prow = wave * 16 + lr;

    const unsigned short* q16 = (const unsigned short*)qkv;
    const float inv7 = 1.f / 7.f;   // 49^-0.5
    const short8 zf = (short8){0, 0, 0, 0, 0, 0, 0, 0};

    short8 qf[4][2];
    #pragma unroll
    for (int it = 0; it < 4; ++it) {
        const unsigned short* qrow = q16 + (base + i0w + it * 16 + lr) * 168;
        #pragma unroll
        for (int kst = 0; kst < 2; ++kst) {
            int k0 = lk * 8 + kst * 32;
            qf[it][kst] = (k0 <= 48) ? *(const short8*)(qrow + k0) : zf;
        }
    }

    float m_run[4], l_run[4];
    f32x4 acc_o[4][4];   // [dt][it]
    #pragma unroll
    for (int it = 0; it < 4; ++it) { m_run[it] = -1e30f; l_run[it] = 0.f; }
    #pragma unroll
    for (int dt = 0; dt < 4; ++dt)
        #pragma unroll
        for (int it = 0; it < 4; ++it) acc_o[dt][it] = (f32x4){0.f, 0.f, 0.f, 0.f};

    for (int jt4 = 0; jt4 < 4; ++jt4) {
        const int j0 = jt4 * 64;
        {
            const int jr = tid >> 3, c8 = (tid & 7) * 8;
            #pragma unroll
            for (int h = 0; h < 2; ++h) {
                int jj = jr + h * 32;
                const unsigned short* row = q16 + (base + j0 + jj) * 168;
                *(short8*)&K_lds[jj][c8]    = (c8 <= 48) ? *(const short8*)(row + 56 + c8) : zf;
                *(short8*)&P_lds[0][jj][c8] = (c8 <= 48) ? *(const short8*)(row + 112 + c8) : zf;
            }
        }
        __syncthreads();
        {
            const int jj = tid & 63, dg = tid >> 6;
            #pragma unroll
            for (int e = 0; e < 16; ++e) {
                int d = dg * 16 + e;
                VT_lds[d][jj] = P_lds[0][jj][d];
            }
        }
        __syncthreads();

        #pragma unroll
        for (int it = 0; it < 4; ++it) {
            unsigned short* prowp = &P_lds[it & 1][prow][0];
            f32x4 sacc[4];
            #pragma unroll
            for (int jt = 0; jt < 4; ++jt) sacc[jt] = (f32x4){0.f, 0.f, 0.f, 0.f};
            #pragma unroll
            for (int kst = 0; kst < 2; ++kst) {
                #pragma unroll
                for (int jt = 0; jt < 4; ++jt) {
                    short8 af = *(const short8*)&K_lds[jt * 16 + lr][lk * 8 + kst * 32];
                    sacc[jt] = __builtin_amdgcn_mfma_f32_16x16x32_bf16(
                        af, qf[it][kst], sacc[jt], 0, 0, 0);
                }
            }
            float mt = -1e30f;
            #pragma unroll
            for (int jt = 0; jt < 4; ++jt)
                #pragma unroll
                for (int r = 0; r < 4; ++r) mt = fmaxf(mt, sacc[jt][r]);
            mt = fmaxf(mt, __shfl_xor(mt, 16, 64));
            mt = fmaxf(mt, __shfl_xor(mt, 32, 64));
            float mnew = fmaxf(m_run[it], mt * inv7);
            float corr = __expf(m_run[it] - mnew);
            m_run[it] = mnew;
            l_run[it] *= corr;
            #pragma unroll
            for (int dt = 0; dt < 4; ++dt)
                #pragma unroll
                for (int r = 0; r < 4; ++r) acc_o[dt][it][r] *= corr;

            float psum = 0.f;
            #pragma unroll
            for (int jt = 0; jt < 4; ++jt) {
                float p0 = __expf(sacc[jt][0] * inv7 - mnew);
                float p1 = __expf(sacc[jt][1] * inv7 - mnew);
                float p2 = __expf(sacc[jt][2] * inv7 - mnew);
                float p3 = __expf(sacc[jt][3] * inv7 - mnew);
                psum += (p0 + p1) + (p2 + p3);
                uint2 wv;
                wv.x = (unsigned)bf16_bits(p0) | ((unsigned)bf16_bits(p1) << 16);
                wv.y = (unsigned)bf16_bits(p2) | ((unsigned)bf16_bits(p3) << 16);
                *(uint2*)(prowp + jt * 16 + lk * 4) = wv;
            }
            psum += __shfl_xor(psum, 16, 64);
            psum += __shfl_xor(psum, 32, 64);
            l_run[it] += psum;

            #pragma unroll
            for (int kst = 0; kst < 2; ++kst) {
                short8 bfv = *(const short8*)(prowp + kst * 32 + lk * 8);
                #pragma unroll
                for (int dt = 0; dt < 4; ++dt) {
                    short8 af = *(const short8*)&VT_lds[dt * 16 + lr][kst * 32 + lk * 8];
                    acc_o[dt][it] = __builtin_amdgcn_mfma_f32_16x16x32_bf16(
                        af, bfv, acc_o[dt][it], 0, 0, 0);
                }
            }
        }
        __syncthreads();
    }

    #pragma unroll
    for (int it = 0; it < 4; ++it) {
        float inv = 1.f / l_run[it];
        unsigned short* orow = (unsigned short*)outp + (base + i0w + it * 16 + lr) * 64;
        #pragma unroll
        for (int dt = 0; dt < 4; ++dt) {
            uint2 wv;
            wv.x = (unsigned)bf16_bits(acc_o[dt][it][0] * inv)
                 | ((unsigned)bf16_bits(acc_o[dt][it][1] * inv) << 16);
            wv.y = (unsigned)bf16_bits(acc_o[dt][it][2] * inv)
                 | ((unsigned)bf16_bits(acc_o[dt][it][3] * inv) << 16);
            *(uint2*)&orow[dt * 16 + lk * 4] = wv;
        }
    }
}

// ---------------------------------------------------------------------------
// 6a) FUSED transpose + pad: patches -> pc_pad[((b*256+c)*256+p)*64+t]
// ---------------------------------------------------------------------------
__global__ __launch_bounds__(256) void transpose_pad_kernel(
    const __hip_bfloat16* __restrict__ patches, unsigned short* __restrict__ pc_pad)
{
    __shared__ __hip_bfloat16 T[64][66];
    int b = blockIdx.z;
    int r0 = blockIdx.y * 64, c0 = blockIdx.x * 64;
    const __hip_bfloat16* s = patches + (size_t)b * 12544 * 256;
    int tid = threadIdx.x;
    int lr4 = tid >> 6, lc = tid & 63;

    #pragma unroll
    for (int l = 0; l < 16; ++l) {
        int rr = l * 4 + lr4;
        T[rr][lc] = s[(size_t)(r0 + rr) * 256 + c0 + lc];
    }
    __syncthreads();
    int r = r0 + lc;
    int p = r / 49, t = r - p * 49;
    #pragma unroll
    for (int l = 0; l < 16; ++l) {
        int cc = l * 4 + lr4;
        size_t dst = (((size_t)(b * 256 + c0 + cc) * 256) + p) * 64 + t;
        pc_pad[dst] = *(unsigned short*)&T[lc][cc];
    }
    int plo = r0 / 49, phi = (r0 + 63) / 49;
    for (int pp = plo; pp <= phi; ++pp) {
        if (pp >= 256) break;
        for (int idx = tid; idx < 64 * 15; idx += 256) {
            int cc = idx / 15, t2 = 49 + idx % 15;
            size_t dst = (((size_t)(b * 256 + c0 + cc) * 256) + pp) * 64 + t2;
            pc_pad[dst] = 0;
        }
    }
}

// ---------------------------------------------------------------------------
// 6) batched 2D transpose: src[b][R][Cc] -> dst[b][Cc][R]; grid (Cc/64,R/64,B)
// ---------------------------------------------------------------------------
__global__ __launch_bounds__(256) void transpose_bf16_kernel(
    const __hip_bfloat16* __restrict__ src, __hip_bfloat16* __restrict__ dst,
    int R, int Cc)
{
    __shared__ __hip_bfloat16 T[64][66];
    int b = blockIdx.z;
    int r0 = blockIdx.y * 64, c0 = blockIdx.x * 64;
    const __hip_bfloat16* s = src + (size_t)b * R * Cc;
    __hip_bfloat16* d = dst + (size_t)b * R * Cc;
    int tid = threadIdx.x;
    int lr = tid >> 6, lc = tid & 63;

    #pragma unroll
    for (int l = 0; l < 16; ++l) {
        int rr = l * 4 + lr;
        T[rr][lc] = s[(size_t)(r0 + rr) * Cc + c0 + lc];
    }
    __syncthreads();
    #pragma unroll
    for (int l = 0; l < 16; ++l) {
        int cc = l * 4 + lr;
        d[(size_t)(c0 + cc) * R + r0 + lc] = T[lc][cc];
    }
}

// ---------------------------------------------------------------------------
__global__ void ws_marker_kernel(float* __restrict__ out0)
{
    if (threadIdx.x == 0) out0[0] = 777.0f;
}

// ---------------------------------------------------------------------------
extern "C" void kernel_launch(void* const* d_in, const int* in_sizes, int n_in,
                              void* d_out, int out_size, void* d_ws, size_t ws_size,
                              hipStream_t stream)
{
    const float* x        = (const float*)d_in[0];
    const float* gamma    = (const float*)d_in[1];
    const float* beta     = (const float*)d_in[2];
    const float* qkv_l_w  = (const float*)d_in[3];
    const float* qkv_l_b  = (const float*)d_in[4];
    const float* proj_l_w = (const float*)d_in[5];
    const float* proj_l_b = (const float*)d_in[6];
    const float* rpb      = (const float*)d_in[7];
    const float* qkv_c_w  = (const float*)d_in[8];
    const float* qkv_c_b  = (const float*)d_in[9];
    const float* proj_c_w = (const float*)d_in[10];
    const float* proj_c_b = (const float*)d_in[11];
    const float* proj_w   = (const float*)d_in[12];

    float* out0 = (float*)d_out;
    float* out1 = out0 + ELEMS;

    copy_f32_kernel<<<(int)(ELEMS / 1024), 256, 0, stream>>>(x, out1);

    char* ws = (char*)d_ws;
    if (ws_size < 6 * SZ) {
        ws_marker_kernel<<<1, 64, 0, stream>>>(out0);
        return;
    }

    const size_t P = SZ;
    // plane/lifetime map (identical to R19, verified):
    __hip_bfloat16* localOut  = (__hip_bfloat16*)(ws + 0 * P);
    unsigned short* wt_qkv_l  = (unsigned short*)(ws + 0 * P);
    float*          biasb     = (float*)(ws + 0 * P + 0x80000);
    __hip_bfloat16* patches   = (__hip_bfloat16*)(ws + 1 * P);
    __hip_bfloat16* qkv_l     = (__hip_bfloat16*)(ws + 2 * P);
    __hip_bfloat16* attnL     = (__hip_bfloat16*)(ws + 5 * P);
    char*           G         = ws + 4 * P + 0xB00000;
    unsigned short* wt_proj_l = (unsigned short*)(G + 0x000000);
    unsigned short* wt_qkv_c  = (unsigned short*)(G + 0x080000);
    unsigned short* wt_proj_c = (unsigned short*)(G + 0x100000);
    unsigned short* wt_final  = (unsigned short*)(G + 0x180000);
    float*          biasc     = (float*)(G + 0x300000);
    __hip_bfloat16* pc_pad    = (__hip_bfloat16*)(ws + 6 * P - (size_t)262144 * 64 * 2);
    __hip_bfloat16* qkvc      = (__hip_bfloat16*)(ws + 1 * P);
    __hip_bfloat16* crossAttn = pc_pad;
    __hip_bfloat16* crossProj = (__hip_bfloat16*)(ws + 1 * P);
    __hip_bfloat16* crossT    = (__hip_bfloat16*)(ws + 2 * P);

    // K0) combined prep A: wt_qkv_l + biasb (needed before K3/K4)
    prep_a_kernel<<<896, 256, 0, stream>>>(qkv_l_w, wt_qkv_l, rpb, biasb);
    // K1) LN + window partition
    ln_partition_kernel<<<BB * HH * 7, 256, 0, stream>>>(x, gamma, beta, patches);
    // K3) qkv_local: [50176,256] @ [256,768], pitch 768
    gemm_mfma_kernel<<<dim3(12, 392), 256, 0, stream>>>(
        patches, nullptr, 256, wt_qkv_l, qkv_l_b, qkv_l, nullptr, 50176, 768, 256, 768);
    // K4) local attention (MFMA)
    local_attn_mfma_kernel<<<1024 * NHEAD, 64, 0, stream>>>(qkv_l, biasb, attnL);
    // K4.5) combined prep B (G region free after K4)
    prep_b_kernel<<<833, 256, 0, stream>>>(
        proj_l_w, wt_proj_l, qkv_c_w, wt_qkv_c, qkv_c_b, biasc,
        proj_c_w, wt_proj_c, proj_w, wt_final);
    // K5) proj_local: [50176,256] @ [256,256], pitch 256
    gemm_mfma_kernel<<<dim3(4, 392), 256, 0, stream>>>(
        attnL, nullptr, 256, wt_proj_l, proj_l_b, localOut, nullptr, 50176, 256, 256, 256);
    // K6) fused transpose+pad: patches -> pc_pad [262144][64]
    transpose_pad_kernel<<<dim3(4, 196, BB), 256, 0, stream>>>(
        patches, (unsigned short*)pc_pad);
    // K7) qkv_cross: [262144,64pad] @ [64,161 remapped] -> qkvc pitch 168
    gemm_mfma_kernel<<<dim3(3, 2048), 256, 0, stream>>>(
        pc_pad, nullptr, 64, wt_qkv_c, biasc, qkvc, nullptr, 262144, 161, 64, 168);
    // K8) cross attention (reads pitch 168, aligned segments)
    cross_attn_mfma_kernel<<<1024, 256, 0, stream>>>(qkvc, crossAttn);
    // K9) proj_cross: [262144,64pad] @ [64,49] -> dense [262144][49]
    gemm_mfma_kernel<<<dim3(1, 2048), 256, 0, stream>>>(
        crossAttn, nullptr, 64, wt_proj_c, proj_c_b, crossProj, nullptr, 262144, 49, 64, 49);
    // K10) crossT = per-b transpose back
    transpose_bf16_kernel<<<dim3(196, 4, BB), 256, 0, stream>>>(crossProj, crossT, 256, 12544);
    // K11) final: concat[localOut|crossT] @ proj_w -> out0 fp32 BCHW (staged epilogue)
    gemm_mfma_kernel<<<dim3(4, 392), 256, 0, stream>>>(
        localOut, crossT, 256, wt_final, nullptr, nullptr, out0, 50176, 256, 512, 256);
}